// Round 7
// baseline (893.149 us; speedup 1.0000x reference)
//
#include <hip/hip_runtime.h>

#define NN 100000     // nodes
#define NE 1600000    // edges
#define NG 512        // graphs
#define C_H1 64
#define C_H2 128
#define C_OUT 2

#define SCAN_CHUNK 512
#define SCAN_B ((NN + SCAN_CHUNK - 1) / SCAN_CHUNK)   // 196
#define MM2_BLOCKS ((NN + 63) / 64)                   // 1563
#define NB ((NN + 255) >> 8)                          // 391 dst-buckets of 256 nodes

// ---------------- degree histogram (at dst) ----------------
__global__ void k_deg(const int* __restrict__ ei, int* __restrict__ deg) {
    int e = blockIdx.x * blockDim.x + threadIdx.x;
    if (e < NE) atomicAdd(&deg[ei[NE + e]], 1);
}

__global__ void k_dinv(const int* __restrict__ deg, float* __restrict__ dinv) {
    int i = blockIdx.x * blockDim.x + threadIdx.x;
    if (i < NN) dinv[i] = rsqrtf((float)deg[i] + 1.0f);
}

// ---------------- hierarchical scan phase 1: per-block sums ----------------
__global__ void k_bsum(const int* __restrict__ deg, int* __restrict__ bsum) {
    __shared__ int sh[256];
    int tid = threadIdx.x;
    int base = blockIdx.x * SCAN_CHUNK + tid * 2;
    int s = 0;
    if (base < NN)     s += deg[base];
    if (base + 1 < NN) s += deg[base + 1];
    sh[tid] = s;
    __syncthreads();
    for (int off = 128; off > 0; off >>= 1) {
        if (tid < off) sh[tid] += sh[tid + off];
        __syncthreads();
    }
    if (tid == 0) bsum[blockIdx.x] = sh[0];
}

// ---------------- phase 2: single small block scans the 196 block sums -----------
__global__ void k_bscan(const int* __restrict__ bsum, int* __restrict__ boff,
                        int* __restrict__ row_ptr) {
    __shared__ int sh[256];
    int tid = threadIdx.x;
    sh[tid] = (tid < SCAN_B) ? bsum[tid] : 0;
    __syncthreads();
    for (int off = 1; off < 256; off <<= 1) {
        int v = (tid >= off) ? sh[tid - off] : 0;
        __syncthreads();
        sh[tid] += v;
        __syncthreads();
    }
    if (tid < SCAN_B) boff[tid] = (tid == 0) ? 0 : sh[tid - 1];
    if (tid == 255) row_ptr[NN] = sh[SCAN_B - 1];   // total == NE
}

// ---------------- phase 3: in-block scan + write row_ptr/cursor/bucket-cursor ----
__global__ void k_bwrite(const int* __restrict__ deg, const int* __restrict__ boff,
                         int* __restrict__ row_ptr, int* __restrict__ bcur) {
    __shared__ int sh[256];
    int tid = threadIdx.x;
    int base = blockIdx.x * SCAN_CHUNK + tid * 2;
    int d0 = (base < NN)     ? deg[base]     : 0;
    int d1 = (base + 1 < NN) ? deg[base + 1] : 0;
    sh[tid] = d0 + d1;
    __syncthreads();
    for (int off = 1; off < 256; off <<= 1) {
        int v = (tid >= off) ? sh[tid - off] : 0;
        __syncthreads();
        sh[tid] += v;
        __syncthreads();
    }
    int excl = boff[blockIdx.x] + ((tid == 0) ? 0 : sh[tid - 1]);
    if (base < NN) {
        row_ptr[base] = excl;
        if ((base & 255) == 0) bcur[base >> 8] = excl;  // bucket staging cursor init
    }
    if (base + 1 < NN) row_ptr[base + 1] = excl + d0;
}

// ---------------- scatter pass A: bin edges by dst>>8 into staging (dense) -------
__global__ void k_scatterA(const int* __restrict__ ei, int* __restrict__ bcur,
                           int2* __restrict__ ed2) {
    int e = blockIdx.x * blockDim.x + threadIdx.x;
    if (e >= NE) return;
    int s = ei[e], d = ei[NE + e];
    int pos = atomicAdd(&bcur[d >> 8], 1);
    int2 v; v.x = s; v.y = d;
    ed2[pos] = v;      // appends within the bucket's contiguous region -> no write amp
}

// ---------------- scatter pass B: bucket-local resolve into final CSR ------------
// One block per bucket; LDS cursors; ed writes land in a ~32KB window.
__global__ void k_scatterB(const int* __restrict__ row_ptr, const int2* __restrict__ ed2,
                           const float* __restrict__ dinv, int2* __restrict__ ed) {
    __shared__ int   lcur[256];
    __shared__ float ldin[256];
    int b = blockIdx.x;
    int lo = b << 8;
    int tid = threadIdx.x;
    int node = lo + tid;
    if (node <= NN) lcur[tid] = row_ptr[node < NN ? node : NN];
    else            lcur[tid] = 0;
    ldin[tid] = (node < NN) ? dinv[node] : 0.f;
    __syncthreads();
    int seg_beg = row_ptr[lo];
    int hi = lo + 256; if (hi > NN) hi = NN;
    int seg_end = row_ptr[hi];
    for (int j = seg_beg + tid; j < seg_end; j += 256) {
        int2 sd = ed2[j];
        int local = sd.y - lo;
        int pos = atomicAdd(&lcur[local], 1);
        int2 v; v.x = sd.x; v.y = __float_as_int(dinv[sd.x] * ldin[local]);
        ed[pos] = v;
    }
}

// ---------------- layer 1 aggregate FIRST (3 channels, x is L2-resident) ----------
__global__ void k_aggx(const int* __restrict__ row_ptr, const int2* __restrict__ ed,
                       const float* __restrict__ dinv, const float* __restrict__ x,
                       float* __restrict__ aggx) {
    int n = blockIdx.x * blockDim.x + threadIdx.x;
    if (n >= NN) return;
    float di = dinv[n];
    float s2 = di * di;
    float a0 = s2 * x[n * 3], a1 = s2 * x[n * 3 + 1], a2 = s2 * x[n * 3 + 2];
    int beg = row_ptr[n], end = row_ptr[n + 1];
    for (int j = beg; j < end; ++j) {
        int2 v = ed[j];
        float w = __int_as_float(v.y);
        const float* xs = x + v.x * 3;
        a0 = fmaf(w, xs[0], a0);
        a1 = fmaf(w, xs[1], a1);
        a2 = fmaf(w, xs[2], a2);
    }
    aggx[n * 3]     = a0;
    aggx[n * 3 + 1] = a1;
    aggx[n * 3 + 2] = a2;
}

// ---------------- h1 = relu(aggx @ W1 + b1) ----------------
__global__ void k_h1(const float* __restrict__ aggx, const float* __restrict__ W1,
                     const float* __restrict__ b1, float* __restrict__ h1) {
    int t = blockIdx.x * blockDim.x + threadIdx.x;
    if (t >= NN * C_H1) return;
    int n = t >> 6, c = t & 63;
    float v = aggx[n * 3] * W1[c] + aggx[n * 3 + 1] * W1[64 + c]
            + aggx[n * 3 + 2] * W1[128 + c] + b1[c];
    h1[t] = fmaxf(v, 0.f);
}

// ---------------- layer 2 aggregate (64 channels): agg1 = Ahat @ h1 --------------
__global__ void k_gather2(const int* __restrict__ row_ptr, const int2* __restrict__ ed,
                          const float* __restrict__ dinv, const float* __restrict__ h1,
                          float* __restrict__ agg1) {
    int t = blockIdx.x * blockDim.x + threadIdx.x;   // wave = one node (64 ch)
    if (t >= NN * C_H1) return;
    int n = t >> 6, c = t & 63;
    float di = dinv[n];
    float acc = di * di * h1[t];                     // self-loop
    int beg = row_ptr[n], end = row_ptr[n + 1];
    int j = beg;
    for (; j + 3 < end; j += 4) {
        int2 v0 = ed[j], v1 = ed[j + 1], v2 = ed[j + 2], v3 = ed[j + 3];
        float f0 = h1[(v0.x << 6) + c];
        float f1 = h1[(v1.x << 6) + c];
        float f2 = h1[(v2.x << 6) + c];
        float f3 = h1[(v3.x << 6) + c];
        acc = fmaf(__int_as_float(v0.y), f0, acc);
        acc = fmaf(__int_as_float(v1.y), f1, acc);
        acc = fmaf(__int_as_float(v2.y), f2, acc);
        acc = fmaf(__int_as_float(v3.y), f3, acc);
    }
    for (; j < end; ++j) {
        int2 v = ed[j];
        acc = fmaf(__int_as_float(v.y), h1[(v.x << 6) + c], acc);
    }
    agg1[t] = acc;   // NO bias/relu here: h2 = relu(agg1 @ W2 + b2)
}

// ---------------- fused register-tiled GEMM + pool --------------------------------
__global__ void k_mm2pool(const float* __restrict__ agg1, const float* __restrict__ W2,
                          const float* __restrict__ b2, const int* __restrict__ batch,
                          float* __restrict__ pooled) {
    __shared__ float wt[C_H1 * C_H2];   // 32 KiB
    __shared__ float at[64 * C_H1];     // 16 KiB
    int tid = threadIdx.x;
    {
        const float4* w4 = (const float4*)W2;
        float4* wl = (float4*)wt;
        for (int i = tid; i < (C_H1 * C_H2) / 4; i += 256) wl[i] = w4[i];
        const float4* a4 = (const float4*)(agg1 + (size_t)blockIdx.x * 64 * C_H1);
        float4* al = (float4*)at;
        for (int i = tid; i < (64 * C_H1) / 4; i += 256) al[i] = a4[i];
    }
    __syncthreads();

    int tx = tid & 31;
    int my = tid >> 5;
    int c0 = tx * 4;
    int m0 = my * 8;

    float acc[8][4];
#pragma unroll
    for (int i = 0; i < 8; ++i)
#pragma unroll
        for (int j = 0; j < 4; ++j) acc[i][j] = 0.f;

    for (int k0 = 0; k0 < C_H1; k0 += 4) {
        float4 wf[4];
#pragma unroll
        for (int kk = 0; kk < 4; ++kk)
            wf[kk] = *(const float4*)&wt[(k0 + kk) * C_H2 + c0];
#pragma unroll
        for (int i = 0; i < 8; ++i) {
            float4 af = *(const float4*)&at[(m0 + i) * C_H1 + k0];
            acc[i][0] = fmaf(af.x, wf[0].x, acc[i][0]);
            acc[i][1] = fmaf(af.x, wf[0].y, acc[i][1]);
            acc[i][2] = fmaf(af.x, wf[0].z, acc[i][2]);
            acc[i][3] = fmaf(af.x, wf[0].w, acc[i][3]);
            acc[i][0] = fmaf(af.y, wf[1].x, acc[i][0]);
            acc[i][1] = fmaf(af.y, wf[1].y, acc[i][1]);
            acc[i][2] = fmaf(af.y, wf[1].z, acc[i][2]);
            acc[i][3] = fmaf(af.y, wf[1].w, acc[i][3]);
            acc[i][0] = fmaf(af.z, wf[2].x, acc[i][0]);
            acc[i][1] = fmaf(af.z, wf[2].y, acc[i][1]);
            acc[i][2] = fmaf(af.z, wf[2].z, acc[i][2]);
            acc[i][3] = fmaf(af.z, wf[2].w, acc[i][3]);
            acc[i][0] = fmaf(af.w, wf[3].x, acc[i][0]);
            acc[i][1] = fmaf(af.w, wf[3].y, acc[i][1]);
            acc[i][2] = fmaf(af.w, wf[3].z, acc[i][2]);
            acc[i][3] = fmaf(af.w, wf[3].w, acc[i][3]);
        }
    }

    int nbase = blockIdx.x * 64 + m0;
    int gidx[8];
#pragma unroll
    for (int i = 0; i < 8; ++i)
        gidx[i] = (nbase + i < NN) ? batch[nbase + i] : -1;
    float bias[4];
#pragma unroll
    for (int j = 0; j < 4; ++j) bias[j] = b2[c0 + j];

#pragma unroll
    for (int j = 0; j < 4; ++j) {
        int run_g = -1;
        float rs = 0.f;
#pragma unroll
        for (int i = 0; i < 8; ++i) {
            if (gidx[i] < 0) break;
            float h = fmaxf(acc[i][j] + bias[j], 0.f);
            if (gidx[i] != run_g) {
                if (run_g >= 0) atomicAdd(&pooled[(run_g << 7) + c0 + j], rs);
                run_g = gidx[i]; rs = h;
            } else {
                rs += h;
            }
        }
        if (run_g >= 0) atomicAdd(&pooled[(run_g << 7) + c0 + j], rs);
    }
}

// ---------------- FC: out = (pooled/cnt) @ Wfc + bfc ----------------
__device__ __forceinline__ int lower_bound(const int* __restrict__ a, int n, int key) {
    int lo = 0, hi = n;
    while (lo < hi) { int mid = (lo + hi) >> 1; if (a[mid] < key) lo = mid + 1; else hi = mid; }
    return lo;
}

__global__ void k_fc(const float* __restrict__ pooled, const int* __restrict__ batch,
                     const float* __restrict__ Wfc, const float* __restrict__ bfc,
                     float* __restrict__ out) {
    int t = blockIdx.x * blockDim.x + threadIdx.x;
    if (t >= NG * C_OUT) return;
    int g = t >> 1, o = t & 1;
    int start = lower_bound(batch, NN, g);
    int end   = lower_bound(batch, NN, g + 1);
    float inv = 1.f / fmaxf((float)(end - start), 1.f);
    float s = bfc[o];
    for (int cc = 0; cc < C_H2; ++cc)
        s = fmaf(pooled[(g << 7) + cc] * inv, Wfc[cc * C_OUT + o], s);
    out[t] = s;
}

extern "C" void kernel_launch(void* const* d_in, const int* in_sizes, int n_in,
                              void* d_out, int out_size, void* d_ws, size_t ws_size,
                              hipStream_t stream) {
    const float* x     = (const float*)d_in[0];
    const int*   ei    = (const int*)d_in[1];   // [2, E]: row0 = src, row1 = dst
    const int*   batch = (const int*)d_in[2];
    const float* W1    = (const float*)d_in[3];
    const float* b1    = (const float*)d_in[4];
    const float* W2    = (const float*)d_in[5];
    const float* b2    = (const float*)d_in[6];
    const float* Wfc   = (const float*)d_in[7];
    const float* bfc   = (const float*)d_in[8];
    float* out = (float*)d_out;

    // workspace carve-out (~80 MB)
    char* p = (char*)d_ws;
    auto alloc = [&](size_t bytes) { char* r = p; p += (bytes + 255) & ~size_t(255); return r; };
    int*   deg     = (int*)  alloc((size_t)NN * 4);
    float* dinv    = (float*)alloc((size_t)NN * 4);
    int*   row_ptr = (int*)  alloc((size_t)(NN + 1) * 4);
    int*   bcur    = (int*)  alloc((size_t)NB * 4);
    int*   bsum    = (int*)  alloc((size_t)SCAN_B * 4);
    int*   boff    = (int*)  alloc((size_t)SCAN_B * 4);
    int2*  ed2     = (int2*) alloc((size_t)NE * 8);
    int2*  ed      = (int2*) alloc((size_t)NE * 8);
    float* aggx    = (float*)alloc((size_t)NN * 3 * 4);
    float* h1      = (float*)alloc((size_t)NN * C_H1 * 4);
    float* agg1    = (float*)alloc((size_t)(NN + 64) * C_H1 * 4);  // padded
    float* pooled  = (float*)alloc((size_t)NG * C_H2 * 4);

    hipMemsetAsync(deg, 0, (size_t)NN * 4, stream);
    hipMemsetAsync(pooled, 0, (size_t)NG * C_H2 * 4, stream);
    k_deg     <<<NE / 256, 256, 0, stream>>>(ei, deg);
    k_dinv    <<<(NN + 255) / 256, 256, 0, stream>>>(deg, dinv);
    k_bsum    <<<SCAN_B, 256, 0, stream>>>(deg, bsum);
    k_bscan   <<<1, 256, 0, stream>>>(bsum, boff, row_ptr);
    k_bwrite  <<<SCAN_B, 256, 0, stream>>>(deg, boff, row_ptr, bcur);
    k_scatterA<<<NE / 256, 256, 0, stream>>>(ei, bcur, ed2);
    k_scatterB<<<NB, 256, 0, stream>>>(row_ptr, ed2, dinv, ed);
    k_aggx    <<<(NN + 255) / 256, 256, 0, stream>>>(row_ptr, ed, dinv, x, aggx);
    k_h1      <<<(NN * C_H1) / 256, 256, 0, stream>>>(aggx, W1, b1, h1);
    k_gather2 <<<(NN * C_H1) / 256, 256, 0, stream>>>(row_ptr, ed, dinv, h1, agg1);
    k_mm2pool <<<MM2_BLOCKS, 256, 0, stream>>>(agg1, W2, b2, batch, pooled);
    k_fc      <<<(NG * C_OUT + 255) / 256, 256, 0, stream>>>(pooled, batch, Wfc, bfc, out);
}

// Round 8
// 363.585 us; speedup vs baseline: 2.4565x; 2.4565x over previous
//
#include <hip/hip_runtime.h>

#define NN 100000     // nodes
#define NE 1600000    // edges
#define NG 512        // graphs
#define C_H1 64
#define C_H2 128
#define C_OUT 2

#define SCAN_CHUNK 512
#define SCAN_B ((NN + SCAN_CHUNK - 1) / SCAN_CHUNK)   // 196
#define MM2_BLOCKS ((NN + 63) / 64)                   // 1563
#define NB ((NN + 255) >> 8)                          // 391 dst-buckets of 256 nodes
#define PCHUNKS 512                                   // partition chunks
#define PCHUNK_E (NE / PCHUNKS)                       // 3125 edges per chunk

// ---------------- degree histogram (at dst) ----------------
__global__ void k_deg(const int* __restrict__ ei, int* __restrict__ deg) {
    int e = blockIdx.x * blockDim.x + threadIdx.x;
    if (e < NE) atomicAdd(&deg[ei[NE + e]], 1);
}

__global__ void k_dinv(const int* __restrict__ deg, float* __restrict__ dinv) {
    int i = blockIdx.x * blockDim.x + threadIdx.x;
    if (i < NN) dinv[i] = rsqrtf((float)deg[i] + 1.0f);
}

// ---------------- hierarchical scan phase 1: per-block sums ----------------
__global__ void k_bsum(const int* __restrict__ deg, int* __restrict__ bsum) {
    __shared__ int sh[256];
    int tid = threadIdx.x;
    int base = blockIdx.x * SCAN_CHUNK + tid * 2;
    int s = 0;
    if (base < NN)     s += deg[base];
    if (base + 1 < NN) s += deg[base + 1];
    sh[tid] = s;
    __syncthreads();
    for (int off = 128; off > 0; off >>= 1) {
        if (tid < off) sh[tid] += sh[tid + off];
        __syncthreads();
    }
    if (tid == 0) bsum[blockIdx.x] = sh[0];
}

// ---------------- phase 2: single small block scans the 196 block sums -----------
__global__ void k_bscan(const int* __restrict__ bsum, int* __restrict__ boff,
                        int* __restrict__ row_ptr) {
    __shared__ int sh[256];
    int tid = threadIdx.x;
    sh[tid] = (tid < SCAN_B) ? bsum[tid] : 0;
    __syncthreads();
    for (int off = 1; off < 256; off <<= 1) {
        int v = (tid >= off) ? sh[tid - off] : 0;
        __syncthreads();
        sh[tid] += v;
        __syncthreads();
    }
    if (tid < SCAN_B) boff[tid] = (tid == 0) ? 0 : sh[tid - 1];
    if (tid == 255) row_ptr[NN] = sh[SCAN_B - 1];   // total == NE
}

// ---------------- phase 3: in-block scan + write row_ptr ----------
__global__ void k_bwrite(const int* __restrict__ deg, const int* __restrict__ boff,
                         int* __restrict__ row_ptr) {
    __shared__ int sh[256];
    int tid = threadIdx.x;
    int base = blockIdx.x * SCAN_CHUNK + tid * 2;
    int d0 = (base < NN)     ? deg[base]     : 0;
    int d1 = (base + 1 < NN) ? deg[base + 1] : 0;
    sh[tid] = d0 + d1;
    __syncthreads();
    for (int off = 1; off < 256; off <<= 1) {
        int v = (tid >= off) ? sh[tid - off] : 0;
        __syncthreads();
        sh[tid] += v;
        __syncthreads();
    }
    int excl = boff[blockIdx.x] + ((tid == 0) ? 0 : sh[tid - 1]);
    if (base < NN)     row_ptr[base]     = excl;
    if (base + 1 < NN) row_ptr[base + 1] = excl + d0;
}

// ---------------- radix partition phase 1: per-chunk bucket histograms -----------
// hist layout: hist[bucket * PCHUNKS + chunk]
__global__ void k_hist(const int* __restrict__ ei, int* __restrict__ hist) {
    __shared__ int lh[NB];
    int tid = threadIdx.x;
    int blk = blockIdx.x;
    for (int i = tid; i < NB; i += 256) lh[i] = 0;
    __syncthreads();
    int base = blk * PCHUNK_E;
    for (int e = base + tid; e < base + PCHUNK_E; e += 256)
        atomicAdd(&lh[ei[NE + e] >> 8], 1);
    __syncthreads();
    for (int i = tid; i < NB; i += 256) hist[i * PCHUNKS + blk] = lh[i];
}

// ---------------- radix partition phase 2: per-bucket scan over chunks -----------
// offs[bucket * PCHUNKS + chunk] = row_ptr[bucket<<8] + sum of earlier chunks
__global__ void k_colscan(const int* __restrict__ hist, const int* __restrict__ row_ptr,
                          int* __restrict__ offs) {
    __shared__ int sh[256];
    int b = blockIdx.x;
    int tid = threadIdx.x;
    int v0 = hist[b * PCHUNKS + 2 * tid];
    int v1 = hist[b * PCHUNKS + 2 * tid + 1];
    sh[tid] = v0 + v1;
    __syncthreads();
    for (int off = 1; off < 256; off <<= 1) {
        int v = (tid >= off) ? sh[tid - off] : 0;
        __syncthreads();
        sh[tid] += v;
        __syncthreads();
    }
    int base = row_ptr[b << 8] + ((tid == 0) ? 0 : sh[tid - 1]);
    offs[b * PCHUNKS + 2 * tid]     = base;
    offs[b * PCHUNKS + 2 * tid + 1] = base + v0;
}

// ---------------- radix partition phase 3: scatter via LDS cursors (no atomics) --
__global__ void k_scatterA(const int* __restrict__ ei, const int* __restrict__ offs,
                           int2* __restrict__ ed2) {
    __shared__ int lcur[NB];
    int tid = threadIdx.x;
    int blk = blockIdx.x;
    for (int i = tid; i < NB; i += 256) lcur[i] = offs[i * PCHUNKS + blk];
    __syncthreads();
    int base = blk * PCHUNK_E;
    for (int e = base + tid; e < base + PCHUNK_E; e += 256) {
        int s = ei[e], d = ei[NE + e];
        int pos = atomicAdd(&lcur[d >> 8], 1);     // LDS atomic, low contention
        int2 v; v.x = s; v.y = d;
        ed2[pos] = v;
    }
}

// ---------------- scatter pass B: bucket-local resolve into final CSR ------------
__global__ void k_scatterB(const int* __restrict__ row_ptr, const int2* __restrict__ ed2,
                           const float* __restrict__ dinv, int2* __restrict__ ed) {
    __shared__ int   lcur[256];
    __shared__ float ldin[256];
    int b = blockIdx.x;
    int lo = b << 8;
    int tid = threadIdx.x;
    int node = lo + tid;
    if (node <= NN) lcur[tid] = row_ptr[node < NN ? node : NN];
    else            lcur[tid] = 0;
    ldin[tid] = (node < NN) ? dinv[node] : 0.f;
    __syncthreads();
    int seg_beg = row_ptr[lo];
    int hi = lo + 256; if (hi > NN) hi = NN;
    int seg_end = row_ptr[hi];
    for (int j = seg_beg + tid; j < seg_end; j += 256) {
        int2 sd = ed2[j];
        int local = sd.y - lo;
        int pos = atomicAdd(&lcur[local], 1);
        int2 v; v.x = sd.x; v.y = __float_as_int(dinv[sd.x] * ldin[local]);
        ed[pos] = v;
    }
}

// ---------------- layer 1 aggregate FIRST (3 channels, x is L2-resident) ----------
__global__ void k_aggx(const int* __restrict__ row_ptr, const int2* __restrict__ ed,
                       const float* __restrict__ dinv, const float* __restrict__ x,
                       float* __restrict__ aggx) {
    int n = blockIdx.x * blockDim.x + threadIdx.x;
    if (n >= NN) return;
    float di = dinv[n];
    float s2 = di * di;
    float a0 = s2 * x[n * 3], a1 = s2 * x[n * 3 + 1], a2 = s2 * x[n * 3 + 2];
    int beg = row_ptr[n], end = row_ptr[n + 1];
    for (int j = beg; j < end; ++j) {
        int2 v = ed[j];
        float w = __int_as_float(v.y);
        const float* xs = x + v.x * 3;
        a0 = fmaf(w, xs[0], a0);
        a1 = fmaf(w, xs[1], a1);
        a2 = fmaf(w, xs[2], a2);
    }
    aggx[n * 3]     = a0;
    aggx[n * 3 + 1] = a1;
    aggx[n * 3 + 2] = a2;
}

// ---------------- h1 = relu(aggx @ W1 + b1) ----------------
__global__ void k_h1(const float* __restrict__ aggx, const float* __restrict__ W1,
                     const float* __restrict__ b1, float* __restrict__ h1) {
    int t = blockIdx.x * blockDim.x + threadIdx.x;
    if (t >= NN * C_H1) return;
    int n = t >> 6, c = t & 63;
    float v = aggx[n * 3] * W1[c] + aggx[n * 3 + 1] * W1[64 + c]
            + aggx[n * 3 + 2] * W1[128 + c] + b1[c];
    h1[t] = fmaxf(v, 0.f);
}

// ---------------- layer 2 aggregate (64 channels): agg1 = Ahat @ h1 --------------
__global__ void k_gather2(const int* __restrict__ row_ptr, const int2* __restrict__ ed,
                          const float* __restrict__ dinv, const float* __restrict__ h1,
                          float* __restrict__ agg1) {
    int t = blockIdx.x * blockDim.x + threadIdx.x;   // wave = one node (64 ch)
    if (t >= NN * C_H1) return;
    int n = t >> 6, c = t & 63;
    float di = dinv[n];
    float acc = di * di * h1[t];                     // self-loop
    int beg = row_ptr[n], end = row_ptr[n + 1];
    int j = beg;
    for (; j + 3 < end; j += 4) {
        int2 v0 = ed[j], v1 = ed[j + 1], v2 = ed[j + 2], v3 = ed[j + 3];
        float f0 = h1[(v0.x << 6) + c];
        float f1 = h1[(v1.x << 6) + c];
        float f2 = h1[(v2.x << 6) + c];
        float f3 = h1[(v3.x << 6) + c];
        acc = fmaf(__int_as_float(v0.y), f0, acc);
        acc = fmaf(__int_as_float(v1.y), f1, acc);
        acc = fmaf(__int_as_float(v2.y), f2, acc);
        acc = fmaf(__int_as_float(v3.y), f3, acc);
    }
    for (; j < end; ++j) {
        int2 v = ed[j];
        acc = fmaf(__int_as_float(v.y), h1[(v.x << 6) + c], acc);
    }
    agg1[t] = acc;   // NO bias/relu here: h2 = relu(agg1 @ W2 + b2)
}

// ---------------- fused register-tiled GEMM + pool --------------------------------
__global__ void k_mm2pool(const float* __restrict__ agg1, const float* __restrict__ W2,
                          const float* __restrict__ b2, const int* __restrict__ batch,
                          float* __restrict__ pooled) {
    __shared__ float wt[C_H1 * C_H2];   // 32 KiB
    __shared__ float at[64 * C_H1];     // 16 KiB
    int tid = threadIdx.x;
    {
        const float4* w4 = (const float4*)W2;
        float4* wl = (float4*)wt;
        for (int i = tid; i < (C_H1 * C_H2) / 4; i += 256) wl[i] = w4[i];
        const float4* a4 = (const float4*)(agg1 + (size_t)blockIdx.x * 64 * C_H1);
        float4* al = (float4*)at;
        for (int i = tid; i < (64 * C_H1) / 4; i += 256) al[i] = a4[i];
    }
    __syncthreads();

    int tx = tid & 31;
    int my = tid >> 5;
    int c0 = tx * 4;
    int m0 = my * 8;

    float acc[8][4];
#pragma unroll
    for (int i = 0; i < 8; ++i)
#pragma unroll
        for (int j = 0; j < 4; ++j) acc[i][j] = 0.f;

    for (int k0 = 0; k0 < C_H1; k0 += 4) {
        float4 wf[4];
#pragma unroll
        for (int kk = 0; kk < 4; ++kk)
            wf[kk] = *(const float4*)&wt[(k0 + kk) * C_H2 + c0];
#pragma unroll
        for (int i = 0; i < 8; ++i) {
            float4 af = *(const float4*)&at[(m0 + i) * C_H1 + k0];
            acc[i][0] = fmaf(af.x, wf[0].x, acc[i][0]);
            acc[i][1] = fmaf(af.x, wf[0].y, acc[i][1]);
            acc[i][2] = fmaf(af.x, wf[0].z, acc[i][2]);
            acc[i][3] = fmaf(af.x, wf[0].w, acc[i][3]);
            acc[i][0] = fmaf(af.y, wf[1].x, acc[i][0]);
            acc[i][1] = fmaf(af.y, wf[1].y, acc[i][1]);
            acc[i][2] = fmaf(af.y, wf[1].z, acc[i][2]);
            acc[i][3] = fmaf(af.y, wf[1].w, acc[i][3]);
            acc[i][0] = fmaf(af.z, wf[2].x, acc[i][0]);
            acc[i][1] = fmaf(af.z, wf[2].y, acc[i][1]);
            acc[i][2] = fmaf(af.z, wf[2].z, acc[i][2]);
            acc[i][3] = fmaf(af.z, wf[2].w, acc[i][3]);
            acc[i][0] = fmaf(af.w, wf[3].x, acc[i][0]);
            acc[i][1] = fmaf(af.w, wf[3].y, acc[i][1]);
            acc[i][2] = fmaf(af.w, wf[3].z, acc[i][2]);
            acc[i][3] = fmaf(af.w, wf[3].w, acc[i][3]);
        }
    }

    int nbase = blockIdx.x * 64 + m0;
    int gidx[8];
#pragma unroll
    for (int i = 0; i < 8; ++i)
        gidx[i] = (nbase + i < NN) ? batch[nbase + i] : -1;
    float bias[4];
#pragma unroll
    for (int j = 0; j < 4; ++j) bias[j] = b2[c0 + j];

#pragma unroll
    for (int j = 0; j < 4; ++j) {
        int run_g = -1;
        float rs = 0.f;
#pragma unroll
        for (int i = 0; i < 8; ++i) {
            if (gidx[i] < 0) break;
            float h = fmaxf(acc[i][j] + bias[j], 0.f);
            if (gidx[i] != run_g) {
                if (run_g >= 0) atomicAdd(&pooled[(run_g << 7) + c0 + j], rs);
                run_g = gidx[i]; rs = h;
            } else {
                rs += h;
            }
        }
        if (run_g >= 0) atomicAdd(&pooled[(run_g << 7) + c0 + j], rs);
    }
}

// ---------------- FC: out = (pooled/cnt) @ Wfc + bfc ----------------
__device__ __forceinline__ int lower_bound(const int* __restrict__ a, int n, int key) {
    int lo = 0, hi = n;
    while (lo < hi) { int mid = (lo + hi) >> 1; if (a[mid] < key) lo = mid + 1; else hi = mid; }
    return lo;
}

__global__ void k_fc(const float* __restrict__ pooled, const int* __restrict__ batch,
                     const float* __restrict__ Wfc, const float* __restrict__ bfc,
                     float* __restrict__ out) {
    int t = blockIdx.x * blockDim.x + threadIdx.x;
    if (t >= NG * C_OUT) return;
    int g = t >> 1, o = t & 1;
    int start = lower_bound(batch, NN, g);
    int end   = lower_bound(batch, NN, g + 1);
    float inv = 1.f / fmaxf((float)(end - start), 1.f);
    float s = bfc[o];
    for (int cc = 0; cc < C_H2; ++cc)
        s = fmaf(pooled[(g << 7) + cc] * inv, Wfc[cc * C_OUT + o], s);
    out[t] = s;
}

extern "C" void kernel_launch(void* const* d_in, const int* in_sizes, int n_in,
                              void* d_out, int out_size, void* d_ws, size_t ws_size,
                              hipStream_t stream) {
    const float* x     = (const float*)d_in[0];
    const int*   ei    = (const int*)d_in[1];   // [2, E]: row0 = src, row1 = dst
    const int*   batch = (const int*)d_in[2];
    const float* W1    = (const float*)d_in[3];
    const float* b1    = (const float*)d_in[4];
    const float* W2    = (const float*)d_in[5];
    const float* b2    = (const float*)d_in[6];
    const float* Wfc   = (const float*)d_in[7];
    const float* bfc   = (const float*)d_in[8];
    float* out = (float*)d_out;

    // workspace carve-out (~82 MB)
    char* p = (char*)d_ws;
    auto alloc = [&](size_t bytes) { char* r = p; p += (bytes + 255) & ~size_t(255); return r; };
    int*   deg     = (int*)  alloc((size_t)NN * 4);
    float* dinv    = (float*)alloc((size_t)NN * 4);
    int*   row_ptr = (int*)  alloc((size_t)(NN + 1) * 4);
    int*   bsum    = (int*)  alloc((size_t)SCAN_B * 4);
    int*   boff    = (int*)  alloc((size_t)SCAN_B * 4);
    int*   hist    = (int*)  alloc((size_t)NB * PCHUNKS * 4);
    int*   offs    = (int*)  alloc((size_t)NB * PCHUNKS * 4);
    int2*  ed2     = (int2*) alloc((size_t)NE * 8);
    int2*  ed      = (int2*) alloc((size_t)NE * 8);
    float* aggx    = (float*)alloc((size_t)NN * 3 * 4);
    float* h1      = (float*)alloc((size_t)NN * C_H1 * 4);
    float* agg1    = (float*)alloc((size_t)(NN + 64) * C_H1 * 4);  // padded
    float* pooled  = (float*)alloc((size_t)NG * C_H2 * 4);

    hipMemsetAsync(deg, 0, (size_t)NN * 4, stream);
    hipMemsetAsync(pooled, 0, (size_t)NG * C_H2 * 4, stream);
    k_deg     <<<NE / 256, 256, 0, stream>>>(ei, deg);
    k_dinv    <<<(NN + 255) / 256, 256, 0, stream>>>(deg, dinv);
    k_bsum    <<<SCAN_B, 256, 0, stream>>>(deg, bsum);
    k_bscan   <<<1, 256, 0, stream>>>(bsum, boff, row_ptr);
    k_bwrite  <<<SCAN_B, 256, 0, stream>>>(deg, boff, row_ptr);
    k_hist    <<<PCHUNKS, 256, 0, stream>>>(ei, hist);
    k_colscan <<<NB, 256, 0, stream>>>(hist, row_ptr, offs);
    k_scatterA<<<PCHUNKS, 256, 0, stream>>>(ei, offs, ed2);
    k_scatterB<<<NB, 256, 0, stream>>>(row_ptr, ed2, dinv, ed);
    k_aggx    <<<(NN + 255) / 256, 256, 0, stream>>>(row_ptr, ed, dinv, x, aggx);
    k_h1      <<<(NN * C_H1) / 256, 256, 0, stream>>>(aggx, W1, b1, h1);
    k_gather2 <<<(NN * C_H1) / 256, 256, 0, stream>>>(row_ptr, ed, dinv, h1, agg1);
    k_mm2pool <<<MM2_BLOCKS, 256, 0, stream>>>(agg1, W2, b2, batch, pooled);
    k_fc      <<<(NG * C_OUT + 255) / 256, 256, 0, stream>>>(pooled, batch, Wfc, bfc, out);
}

// Round 9
// 313.474 us; speedup vs baseline: 2.8492x; 1.1599x over previous
//
#include <hip/hip_runtime.h>

#define NN 100000     // nodes
#define NE 1600000    // edges
#define NG 512        // graphs
#define C_H1 64
#define C_H2 128
#define C_OUT 2

#define SCAN_CHUNK 512
#define SCAN_B ((NN + SCAN_CHUNK - 1) / SCAN_CHUNK)   // 196
#define MM2_BLOCKS ((NN + 63) / 64)                   // 1563
#define NB ((NN + 255) >> 8)                          // 391 dst-buckets of 256 nodes
#define PCHUNKS 512                                   // partition chunks
#define PCHUNK_E (NE / PCHUNKS)                       // 3125 edges per chunk

// ---------------- degree histogram (at dst) ----------------
__global__ void k_deg(const int* __restrict__ ei, int* __restrict__ deg) {
    int e = blockIdx.x * blockDim.x + threadIdx.x;
    if (e < NE) atomicAdd(&deg[ei[NE + e]], 1);
}

__global__ void k_dinv(const int* __restrict__ deg, float* __restrict__ dinv) {
    int i = blockIdx.x * blockDim.x + threadIdx.x;
    if (i < NN) dinv[i] = rsqrtf((float)deg[i] + 1.0f);
}

// ---------------- hierarchical scan phase 1: per-block sums ----------------
__global__ void k_bsum(const int* __restrict__ deg, int* __restrict__ bsum) {
    __shared__ int sh[256];
    int tid = threadIdx.x;
    int base = blockIdx.x * SCAN_CHUNK + tid * 2;
    int s = 0;
    if (base < NN)     s += deg[base];
    if (base + 1 < NN) s += deg[base + 1];
    sh[tid] = s;
    __syncthreads();
    for (int off = 128; off > 0; off >>= 1) {
        if (tid < off) sh[tid] += sh[tid + off];
        __syncthreads();
    }
    if (tid == 0) bsum[blockIdx.x] = sh[0];
}

// ---------------- phase 2: single small block scans the 196 block sums -----------
__global__ void k_bscan(const int* __restrict__ bsum, int* __restrict__ boff,
                        int* __restrict__ row_ptr) {
    __shared__ int sh[256];
    int tid = threadIdx.x;
    sh[tid] = (tid < SCAN_B) ? bsum[tid] : 0;
    __syncthreads();
    for (int off = 1; off < 256; off <<= 1) {
        int v = (tid >= off) ? sh[tid - off] : 0;
        __syncthreads();
        sh[tid] += v;
        __syncthreads();
    }
    if (tid < SCAN_B) boff[tid] = (tid == 0) ? 0 : sh[tid - 1];
    if (tid == 255) row_ptr[NN] = sh[SCAN_B - 1];   // total == NE
}

// ---------------- phase 3: in-block scan + write row_ptr ----------
__global__ void k_bwrite(const int* __restrict__ deg, const int* __restrict__ boff,
                         int* __restrict__ row_ptr) {
    __shared__ int sh[256];
    int tid = threadIdx.x;
    int base = blockIdx.x * SCAN_CHUNK + tid * 2;
    int d0 = (base < NN)     ? deg[base]     : 0;
    int d1 = (base + 1 < NN) ? deg[base + 1] : 0;
    sh[tid] = d0 + d1;
    __syncthreads();
    for (int off = 1; off < 256; off <<= 1) {
        int v = (tid >= off) ? sh[tid - off] : 0;
        __syncthreads();
        sh[tid] += v;
        __syncthreads();
    }
    int excl = boff[blockIdx.x] + ((tid == 0) ? 0 : sh[tid - 1]);
    if (base < NN)     row_ptr[base]     = excl;
    if (base + 1 < NN) row_ptr[base + 1] = excl + d0;
}

// ---------------- radix partition phase 1: per-chunk bucket histograms -----------
__global__ void k_hist(const int* __restrict__ ei, int* __restrict__ hist) {
    __shared__ int lh[NB];
    int tid = threadIdx.x;
    int blk = blockIdx.x;
    for (int i = tid; i < NB; i += 256) lh[i] = 0;
    __syncthreads();
    int base = blk * PCHUNK_E;
    for (int e = base + tid; e < base + PCHUNK_E; e += 256)
        atomicAdd(&lh[ei[NE + e] >> 8], 1);
    __syncthreads();
    for (int i = tid; i < NB; i += 256) hist[i * PCHUNKS + blk] = lh[i];
}

// ---------------- radix partition phase 2: per-bucket scan over chunks -----------
__global__ void k_colscan(const int* __restrict__ hist, const int* __restrict__ row_ptr,
                          int* __restrict__ offs) {
    __shared__ int sh[256];
    int b = blockIdx.x;
    int tid = threadIdx.x;
    int v0 = hist[b * PCHUNKS + 2 * tid];
    int v1 = hist[b * PCHUNKS + 2 * tid + 1];
    sh[tid] = v0 + v1;
    __syncthreads();
    for (int off = 1; off < 256; off <<= 1) {
        int v = (tid >= off) ? sh[tid - off] : 0;
        __syncthreads();
        sh[tid] += v;
        __syncthreads();
    }
    int base = row_ptr[b << 8] + ((tid == 0) ? 0 : sh[tid - 1]);
    offs[b * PCHUNKS + 2 * tid]     = base;
    offs[b * PCHUNKS + 2 * tid + 1] = base + v0;
}

// ---------------- radix partition phase 3: scatter via LDS cursors ----------------
__global__ void k_scatterA(const int* __restrict__ ei, const int* __restrict__ offs,
                           int2* __restrict__ ed2) {
    __shared__ int lcur[NB];
    int tid = threadIdx.x;
    int blk = blockIdx.x;
    for (int i = tid; i < NB; i += 256) lcur[i] = offs[i * PCHUNKS + blk];
    __syncthreads();
    int base = blk * PCHUNK_E;
    for (int e = base + tid; e < base + PCHUNK_E; e += 256) {
        int s = ei[e], d = ei[NE + e];
        int pos = atomicAdd(&lcur[d >> 8], 1);     // LDS atomic, low contention
        int2 v; v.x = s; v.y = d;
        ed2[pos] = v;
    }
}

// ---------------- scatter pass B: bucket-local resolve into final CSR ------------
__global__ void k_scatterB(const int* __restrict__ row_ptr, const int2* __restrict__ ed2,
                           const float* __restrict__ dinv, int2* __restrict__ ed) {
    __shared__ int   lcur[256];
    __shared__ float ldin[256];
    int b = blockIdx.x;
    int lo = b << 8;
    int tid = threadIdx.x;
    int node = lo + tid;
    if (node <= NN) lcur[tid] = row_ptr[node < NN ? node : NN];
    else            lcur[tid] = 0;
    ldin[tid] = (node < NN) ? dinv[node] : 0.f;
    __syncthreads();
    int seg_beg = row_ptr[lo];
    int hi = lo + 256; if (hi > NN) hi = NN;
    int seg_end = row_ptr[hi];
    for (int j = seg_beg + tid; j < seg_end; j += 256) {
        int2 sd = ed2[j];
        int local = sd.y - lo;
        int pos = atomicAdd(&lcur[local], 1);
        int2 v; v.x = sd.x; v.y = __float_as_int(dinv[sd.x] * ldin[local]);
        ed[pos] = v;
    }
}

// ---------------- layer 1 aggregate (3 channels, x is L2-resident) ----------
__global__ void k_aggx(const int* __restrict__ row_ptr, const int2* __restrict__ ed,
                       const float* __restrict__ dinv, const float* __restrict__ x,
                       float* __restrict__ aggx) {
    int n = blockIdx.x * blockDim.x + threadIdx.x;
    if (n >= NN) return;
    float di = dinv[n];
    float s2 = di * di;
    float a0 = s2 * x[n * 3], a1 = s2 * x[n * 3 + 1], a2 = s2 * x[n * 3 + 2];
    int beg = row_ptr[n], end = row_ptr[n + 1];
    for (int j = beg; j < end; ++j) {
        int2 v = ed[j];
        float w = __int_as_float(v.y);
        const float* xs = x + v.x * 3;
        a0 = fmaf(w, xs[0], a0);
        a1 = fmaf(w, xs[1], a1);
        a2 = fmaf(w, xs[2], a2);
    }
    aggx[n * 3]     = a0;
    aggx[n * 3 + 1] = a1;
    aggx[n * 3 + 2] = a2;
}

// ---------------- per-edge payload: (aggx[src].xyz, norm) in CSR order ----------
__global__ void k_pay(const int2* __restrict__ ed, const float* __restrict__ aggx,
                      float4* __restrict__ pay) {
    int j = blockIdx.x * 256 + threadIdx.x;   // NE/256 = 6250 blocks, exact
    int2 v = ed[j];
    const float* a = aggx + v.x * 3;          // 12 B gather from 1.2 MB (L2-hot)
    float4 p;
    p.x = a[0]; p.y = a[1]; p.z = a[2];
    p.w = __int_as_float(v.y);
    pay[j] = p;
}

// ---------------- layer 2 aggregate via on-the-fly h1 recompute ------------------
// agg1[n][c] = dinv_n^2*h1(n)[c] + sum_e norm_e * h1(src_e)[c],
// h1(m)[c] = relu(aggx[m]·W1[:,c] + b1[c]) recomputed from the 16B payload.
// Wave = one node; payloads staged 64-at-a-time into LDS (coalesced), consumed
// via same-address LDS broadcast (wave-synchronous, no barrier needed).
__global__ void k_edge1(const int* __restrict__ row_ptr, const float4* __restrict__ pay,
                        const float* __restrict__ aggx, const float* __restrict__ dinv,
                        const float* __restrict__ W1, const float* __restrict__ b1,
                        float* __restrict__ agg1) {
    __shared__ float4 lp[256];                        // 64 per wave
    int t = blockIdx.x * 256 + threadIdx.x;           // grid exact: NN*64/256
    int n = t >> 6, c = t & 63;
    int lane = threadIdx.x & 63;
    int wbase = threadIdx.x & 192;                    // wave's LDS base (0,64,128,192)

    float w0 = W1[c], w1 = W1[64 + c], w2 = W1[128 + c], bb = b1[c];
    float a0 = aggx[n * 3], a1 = aggx[n * 3 + 1], a2 = aggx[n * 3 + 2];
    float di = dinv[n];
    float hself = fmaxf(fmaf(a0, w0, fmaf(a1, w1, fmaf(a2, w2, bb))), 0.f);
    float acc = di * di * hself;

    int beg = row_ptr[n], end = row_ptr[n + 1];
    for (int base = beg; base < end; base += 64) {
        int m = end - base; if (m > 64) m = 64;
        if (lane < m) lp[wbase + lane] = pay[base + lane];   // coalesced 16B/lane
        int e = 0;
        for (; e + 3 < m; e += 4) {
            float4 p0 = lp[wbase + e];
            float4 p1 = lp[wbase + e + 1];
            float4 p2 = lp[wbase + e + 2];
            float4 p3 = lp[wbase + e + 3];
            float h0 = fmaxf(fmaf(p0.x, w0, fmaf(p0.y, w1, fmaf(p0.z, w2, bb))), 0.f);
            float h1v = fmaxf(fmaf(p1.x, w0, fmaf(p1.y, w1, fmaf(p1.z, w2, bb))), 0.f);
            float h2v = fmaxf(fmaf(p2.x, w0, fmaf(p2.y, w1, fmaf(p2.z, w2, bb))), 0.f);
            float h3v = fmaxf(fmaf(p3.x, w0, fmaf(p3.y, w1, fmaf(p3.z, w2, bb))), 0.f);
            acc = fmaf(p0.w, h0, acc);
            acc = fmaf(p1.w, h1v, acc);
            acc = fmaf(p2.w, h2v, acc);
            acc = fmaf(p3.w, h3v, acc);
        }
        for (; e < m; ++e) {
            float4 p = lp[wbase + e];
            float h = fmaxf(fmaf(p.x, w0, fmaf(p.y, w1, fmaf(p.z, w2, bb))), 0.f);
            acc = fmaf(p.w, h, acc);
        }
    }
    agg1[t] = acc;   // NO bias/relu here: h2 = relu(agg1 @ W2 + b2)
}

// ---------------- fused register-tiled GEMM + pool --------------------------------
__global__ void k_mm2pool(const float* __restrict__ agg1, const float* __restrict__ W2,
                          const float* __restrict__ b2, const int* __restrict__ batch,
                          float* __restrict__ pooled) {
    __shared__ float wt[C_H1 * C_H2];   // 32 KiB
    __shared__ float at[64 * C_H1];     // 16 KiB
    int tid = threadIdx.x;
    {
        const float4* w4 = (const float4*)W2;
        float4* wl = (float4*)wt;
        for (int i = tid; i < (C_H1 * C_H2) / 4; i += 256) wl[i] = w4[i];
        const float4* a4 = (const float4*)(agg1 + (size_t)blockIdx.x * 64 * C_H1);
        float4* al = (float4*)at;
        for (int i = tid; i < (64 * C_H1) / 4; i += 256) al[i] = a4[i];
    }
    __syncthreads();

    int tx = tid & 31;
    int my = tid >> 5;
    int c0 = tx * 4;
    int m0 = my * 8;

    float acc[8][4];
#pragma unroll
    for (int i = 0; i < 8; ++i)
#pragma unroll
        for (int j = 0; j < 4; ++j) acc[i][j] = 0.f;

    for (int k0 = 0; k0 < C_H1; k0 += 4) {
        float4 wf[4];
#pragma unroll
        for (int kk = 0; kk < 4; ++kk)
            wf[kk] = *(const float4*)&wt[(k0 + kk) * C_H2 + c0];
#pragma unroll
        for (int i = 0; i < 8; ++i) {
            float4 af = *(const float4*)&at[(m0 + i) * C_H1 + k0];
            acc[i][0] = fmaf(af.x, wf[0].x, acc[i][0]);
            acc[i][1] = fmaf(af.x, wf[0].y, acc[i][1]);
            acc[i][2] = fmaf(af.x, wf[0].z, acc[i][2]);
            acc[i][3] = fmaf(af.x, wf[0].w, acc[i][3]);
            acc[i][0] = fmaf(af.y, wf[1].x, acc[i][0]);
            acc[i][1] = fmaf(af.y, wf[1].y, acc[i][1]);
            acc[i][2] = fmaf(af.y, wf[1].z, acc[i][2]);
            acc[i][3] = fmaf(af.y, wf[1].w, acc[i][3]);
            acc[i][0] = fmaf(af.z, wf[2].x, acc[i][0]);
            acc[i][1] = fmaf(af.z, wf[2].y, acc[i][1]);
            acc[i][2] = fmaf(af.z, wf[2].z, acc[i][2]);
            acc[i][3] = fmaf(af.z, wf[2].w, acc[i][3]);
            acc[i][0] = fmaf(af.w, wf[3].x, acc[i][0]);
            acc[i][1] = fmaf(af.w, wf[3].y, acc[i][1]);
            acc[i][2] = fmaf(af.w, wf[3].z, acc[i][2]);
            acc[i][3] = fmaf(af.w, wf[3].w, acc[i][3]);
        }
    }

    int nbase = blockIdx.x * 64 + m0;
    int gidx[8];
#pragma unroll
    for (int i = 0; i < 8; ++i)
        gidx[i] = (nbase + i < NN) ? batch[nbase + i] : -1;
    float bias[4];
#pragma unroll
    for (int j = 0; j < 4; ++j) bias[j] = b2[c0 + j];

#pragma unroll
    for (int j = 0; j < 4; ++j) {
        int run_g = -1;
        float rs = 0.f;
#pragma unroll
        for (int i = 0; i < 8; ++i) {
            if (gidx[i] < 0) break;
            float h = fmaxf(acc[i][j] + bias[j], 0.f);
            if (gidx[i] != run_g) {
                if (run_g >= 0) atomicAdd(&pooled[(run_g << 7) + c0 + j], rs);
                run_g = gidx[i]; rs = h;
            } else {
                rs += h;
            }
        }
        if (run_g >= 0) atomicAdd(&pooled[(run_g << 7) + c0 + j], rs);
    }
}

// ---------------- FC: out = (pooled/cnt) @ Wfc + bfc ----------------
__device__ __forceinline__ int lower_bound(const int* __restrict__ a, int n, int key) {
    int lo = 0, hi = n;
    while (lo < hi) { int mid = (lo + hi) >> 1; if (a[mid] < key) lo = mid + 1; else hi = mid; }
    return lo;
}

__global__ void k_fc(const float* __restrict__ pooled, const int* __restrict__ batch,
                     const float* __restrict__ Wfc, const float* __restrict__ bfc,
                     float* __restrict__ out) {
    int t = blockIdx.x * blockDim.x + threadIdx.x;
    if (t >= NG * C_OUT) return;
    int g = t >> 1, o = t & 1;
    int start = lower_bound(batch, NN, g);
    int end   = lower_bound(batch, NN, g + 1);
    float inv = 1.f / fmaxf((float)(end - start), 1.f);
    float s = bfc[o];
    for (int cc = 0; cc < C_H2; ++cc)
        s = fmaf(pooled[(g << 7) + cc] * inv, Wfc[cc * C_OUT + o], s);
    out[t] = s;
}

extern "C" void kernel_launch(void* const* d_in, const int* in_sizes, int n_in,
                              void* d_out, int out_size, void* d_ws, size_t ws_size,
                              hipStream_t stream) {
    const float* x     = (const float*)d_in[0];
    const int*   ei    = (const int*)d_in[1];   // [2, E]: row0 = src, row1 = dst
    const int*   batch = (const int*)d_in[2];
    const float* W1    = (const float*)d_in[3];
    const float* b1    = (const float*)d_in[4];
    const float* W2    = (const float*)d_in[5];
    const float* b2    = (const float*)d_in[6];
    const float* Wfc   = (const float*)d_in[7];
    const float* bfc   = (const float*)d_in[8];
    float* out = (float*)d_out;

    // workspace carve-out (~95 MB)
    char* p = (char*)d_ws;
    auto alloc = [&](size_t bytes) { char* r = p; p += (bytes + 255) & ~size_t(255); return r; };
    int*    deg     = (int*)   alloc((size_t)NN * 4);
    float*  dinv    = (float*) alloc((size_t)NN * 4);
    int*    row_ptr = (int*)   alloc((size_t)(NN + 1) * 4);
    int*    bsum    = (int*)   alloc((size_t)SCAN_B * 4);
    int*    boff    = (int*)   alloc((size_t)SCAN_B * 4);
    int*    hist    = (int*)   alloc((size_t)NB * PCHUNKS * 4);
    int*    offs    = (int*)   alloc((size_t)NB * PCHUNKS * 4);
    int2*   ed2     = (int2*)  alloc((size_t)NE * 8);
    int2*   ed      = (int2*)  alloc((size_t)NE * 8);
    float*  aggx    = (float*) alloc((size_t)NN * 3 * 4);
    float4* pay     = (float4*)alloc((size_t)NE * 16);
    float*  agg1    = (float*) alloc((size_t)(NN + 64) * C_H1 * 4);  // padded
    float*  pooled  = (float*) alloc((size_t)NG * C_H2 * 4);

    hipMemsetAsync(deg, 0, (size_t)NN * 4, stream);
    hipMemsetAsync(pooled, 0, (size_t)NG * C_H2 * 4, stream);
    k_deg     <<<NE / 256, 256, 0, stream>>>(ei, deg);
    k_dinv    <<<(NN + 255) / 256, 256, 0, stream>>>(deg, dinv);
    k_bsum    <<<SCAN_B, 256, 0, stream>>>(deg, bsum);
    k_bscan   <<<1, 256, 0, stream>>>(bsum, boff, row_ptr);
    k_bwrite  <<<SCAN_B, 256, 0, stream>>>(deg, boff, row_ptr);
    k_hist    <<<PCHUNKS, 256, 0, stream>>>(ei, hist);
    k_colscan <<<NB, 256, 0, stream>>>(hist, row_ptr, offs);
    k_scatterA<<<PCHUNKS, 256, 0, stream>>>(ei, offs, ed2);
    k_scatterB<<<NB, 256, 0, stream>>>(row_ptr, ed2, dinv, ed);
    k_aggx    <<<(NN + 255) / 256, 256, 0, stream>>>(row_ptr, ed, dinv, x, aggx);
    k_pay     <<<NE / 256, 256, 0, stream>>>(ed, aggx, pay);
    k_edge1   <<<(NN * C_H1) / 256, 256, 0, stream>>>(row_ptr, pay, aggx, dinv, W1, b1, agg1);
    k_mm2pool <<<MM2_BLOCKS, 256, 0, stream>>>(agg1, W2, b2, batch, pooled);
    k_fc      <<<(NG * C_OUT + 255) / 256, 256, 0, stream>>>(pooled, batch, Wfc, bfc, out);
}

// Round 10
// 244.052 us; speedup vs baseline: 3.6597x; 1.2845x over previous
//
#include <hip/hip_runtime.h>

#define NN 100000     // nodes
#define NE 1600000    // edges
#define NG 512        // graphs
#define C_H1 64
#define C_H2 128
#define C_OUT 2

#define MM2_BLOCKS ((NN + 63) / 64)                   // 1563
#define NB ((NN + 255) >> 8)                          // 391 dst-buckets of 256 nodes
#define PCHUNKS 512                                   // partition chunks
#define PCHUNK_E (NE / PCHUNKS)                       // 3125 edges per chunk

// ---------------- radix partition phase 1: per-chunk bucket histograms -----------
__global__ void k_hist(const int* __restrict__ ei, int* __restrict__ hist) {
    __shared__ int lh[NB];
    int tid = threadIdx.x;
    int blk = blockIdx.x;
    for (int i = tid; i < NB; i += 256) lh[i] = 0;
    __syncthreads();
    int base = blk * PCHUNK_E;
    for (int e = base + tid; e < base + PCHUNK_E; e += 256)
        atomicAdd(&lh[ei[NE + e] >> 8], 1);
    __syncthreads();
    for (int i = tid; i < NB; i += 256) hist[i * PCHUNKS + blk] = lh[i];
}

// ---------------- phase 2a: per-bucket scan over chunks (bucket-relative) --------
__global__ void k_colscan0(const int* __restrict__ hist, int* __restrict__ offs,
                           int* __restrict__ btot) {
    __shared__ int sh[256];
    int b = blockIdx.x;
    int tid = threadIdx.x;
    int v0 = hist[b * PCHUNKS + 2 * tid];
    int v1 = hist[b * PCHUNKS + 2 * tid + 1];
    sh[tid] = v0 + v1;
    __syncthreads();
    for (int off = 1; off < 256; off <<= 1) {
        int v = (tid >= off) ? sh[tid - off] : 0;
        __syncthreads();
        sh[tid] += v;
        __syncthreads();
    }
    int base = (tid == 0) ? 0 : sh[tid - 1];
    offs[b * PCHUNKS + 2 * tid]     = base;
    offs[b * PCHUNKS + 2 * tid + 1] = base + v0;
    if (tid == 255) btot[b] = sh[255];
}

// ---------------- phase 2b: exclusive scan of 391 bucket totals ------------------
__global__ void k_bbase(const int* __restrict__ btot, int* __restrict__ bbase,
                        int* __restrict__ row_ptr) {
    __shared__ int sh[256];
    int tid = threadIdx.x;
    int v0 = (2 * tid     < NB) ? btot[2 * tid]     : 0;
    int v1 = (2 * tid + 1 < NB) ? btot[2 * tid + 1] : 0;
    sh[tid] = v0 + v1;
    __syncthreads();
    for (int off = 1; off < 256; off <<= 1) {
        int v = (tid >= off) ? sh[tid - off] : 0;
        __syncthreads();
        sh[tid] += v;
        __syncthreads();
    }
    int base = (tid == 0) ? 0 : sh[tid - 1];
    if (2 * tid     < NB) bbase[2 * tid]     = base;
    if (2 * tid + 1 < NB) bbase[2 * tid + 1] = base + v0;
    if (tid == 255) { bbase[NB] = sh[255]; row_ptr[NN] = sh[255]; }   // == NE
}

// ---------------- phase 3: scatter via LDS cursors (no global atomics) -----------
__global__ void k_scatterA(const int* __restrict__ ei, const int* __restrict__ offs,
                           const int* __restrict__ bbase, int2* __restrict__ ed2) {
    __shared__ int lcur[NB];
    int tid = threadIdx.x;
    int blk = blockIdx.x;
    for (int i = tid; i < NB; i += 256) lcur[i] = bbase[i] + offs[i * PCHUNKS + blk];
    __syncthreads();
    int base = blk * PCHUNK_E;
    for (int e = base + tid; e < base + PCHUNK_E; e += 256) {
        int s = ei[e], d = ei[NE + e];
        int pos = atomicAdd(&lcur[d >> 8], 1);     // LDS atomic, low contention
        int2 v; v.x = s; v.y = d;
        ed2[pos] = v;
    }
}

// ---------------- B1: bucket-local degree -> dinv + row_ptr (no global atomics) --
__global__ void k_B1(const int2* __restrict__ ed2, const int* __restrict__ bbase,
                     float* __restrict__ dinv, int* __restrict__ row_ptr) {
    __shared__ int ldeg[256];
    __shared__ int sh[256];
    int b = blockIdx.x;
    int tid = threadIdx.x;
    int lo = b << 8;
    ldeg[tid] = 0;
    __syncthreads();
    int beg = bbase[b], end = bbase[b + 1];
    for (int j = beg + tid; j < end; j += 256)
        atomicAdd(&ldeg[ed2[j].y - lo], 1);
    __syncthreads();
    int d = ldeg[tid];
    int node = lo + tid;
    if (node < NN) dinv[node] = rsqrtf((float)d + 1.0f);
    sh[tid] = d;
    __syncthreads();
    for (int off = 1; off < 256; off <<= 1) {
        int v = (tid >= off) ? sh[tid - off] : 0;
        __syncthreads();
        sh[tid] += v;
        __syncthreads();
    }
    int excl = beg + ((tid == 0) ? 0 : sh[tid - 1]);
    if (node < NN) row_ptr[node] = excl;
}

// ---------------- scatter pass B: bucket-local resolve into final CSR ------------
__global__ void k_scatterB(const int* __restrict__ row_ptr, const int2* __restrict__ ed2,
                           const float* __restrict__ dinv, int2* __restrict__ ed) {
    __shared__ int   lcur[256];
    __shared__ float ldin[256];
    int b = blockIdx.x;
    int lo = b << 8;
    int tid = threadIdx.x;
    int node = lo + tid;
    if (node <= NN) lcur[tid] = row_ptr[node < NN ? node : NN];
    else            lcur[tid] = 0;
    ldin[tid] = (node < NN) ? dinv[node] : 0.f;
    __syncthreads();
    int seg_beg = row_ptr[lo];
    int hi = lo + 256; if (hi > NN) hi = NN;
    int seg_end = row_ptr[hi];
    for (int j = seg_beg + tid; j < seg_end; j += 256) {
        int2 sd = ed2[j];
        int local = sd.y - lo;
        int pos = atomicAdd(&lcur[local], 1);
        int2 v; v.x = sd.x; v.y = __float_as_int(dinv[sd.x] * ldin[local]);
        ed[pos] = v;
    }
}

// ---------------- layer 1 aggregate (3 channels, x is L2-resident) ----------
__global__ void k_aggx(const int* __restrict__ row_ptr, const int2* __restrict__ ed,
                       const float* __restrict__ dinv, const float* __restrict__ x,
                       float* __restrict__ aggx) {
    int n = blockIdx.x * blockDim.x + threadIdx.x;
    if (n >= NN) return;
    float di = dinv[n];
    float s2 = di * di;
    float a0 = s2 * x[n * 3], a1 = s2 * x[n * 3 + 1], a2 = s2 * x[n * 3 + 2];
    int beg = row_ptr[n], end = row_ptr[n + 1];
    for (int j = beg; j < end; ++j) {
        int2 v = ed[j];
        float w = __int_as_float(v.y);
        const float* xs = x + v.x * 3;
        a0 = fmaf(w, xs[0], a0);
        a1 = fmaf(w, xs[1], a1);
        a2 = fmaf(w, xs[2], a2);
    }
    aggx[n * 3]     = a0;
    aggx[n * 3 + 1] = a1;
    aggx[n * 3 + 2] = a2;
}

// ---------------- per-edge payload: (aggx[src].xyz, norm) in CSR order ----------
__global__ void k_pay(const int2* __restrict__ ed, const float* __restrict__ aggx,
                      float4* __restrict__ pay) {
    int j = blockIdx.x * 256 + threadIdx.x;   // NE/256 = 6250 blocks, exact
    int2 v = ed[j];
    const float* a = aggx + v.x * 3;          // 12 B gather from 1.2 MB (L2-hot)
    float4 p;
    p.x = a[0]; p.y = a[1]; p.z = a[2];
    p.w = __int_as_float(v.y);
    pay[j] = p;
}

// ---------------- layer 2 aggregate via on-the-fly h1 recompute ------------------
__global__ void k_edge1(const int* __restrict__ row_ptr, const float4* __restrict__ pay,
                        const float* __restrict__ aggx, const float* __restrict__ dinv,
                        const float* __restrict__ W1, const float* __restrict__ b1,
                        float* __restrict__ agg1) {
    __shared__ float4 lp[256];                        // 64 per wave
    int t = blockIdx.x * 256 + threadIdx.x;           // grid exact: NN*64/256
    int n = t >> 6, c = t & 63;
    int lane = threadIdx.x & 63;
    int wbase = threadIdx.x & 192;                    // wave's LDS base (0,64,128,192)

    float w0 = W1[c], w1 = W1[64 + c], w2 = W1[128 + c], bb = b1[c];
    float a0 = aggx[n * 3], a1 = aggx[n * 3 + 1], a2 = aggx[n * 3 + 2];
    float di = dinv[n];
    float hself = fmaxf(fmaf(a0, w0, fmaf(a1, w1, fmaf(a2, w2, bb))), 0.f);
    float acc = di * di * hself;

    int beg = row_ptr[n], end = row_ptr[n + 1];
    for (int base = beg; base < end; base += 64) {
        int m = end - base; if (m > 64) m = 64;
        if (lane < m) lp[wbase + lane] = pay[base + lane];   // coalesced 16B/lane
        int e = 0;
        for (; e + 3 < m; e += 4) {
            float4 p0 = lp[wbase + e];
            float4 p1 = lp[wbase + e + 1];
            float4 p2 = lp[wbase + e + 2];
            float4 p3 = lp[wbase + e + 3];
            float h0 = fmaxf(fmaf(p0.x, w0, fmaf(p0.y, w1, fmaf(p0.z, w2, bb))), 0.f);
            float h1v = fmaxf(fmaf(p1.x, w0, fmaf(p1.y, w1, fmaf(p1.z, w2, bb))), 0.f);
            float h2v = fmaxf(fmaf(p2.x, w0, fmaf(p2.y, w1, fmaf(p2.z, w2, bb))), 0.f);
            float h3v = fmaxf(fmaf(p3.x, w0, fmaf(p3.y, w1, fmaf(p3.z, w2, bb))), 0.f);
            acc = fmaf(p0.w, h0, acc);
            acc = fmaf(p1.w, h1v, acc);
            acc = fmaf(p2.w, h2v, acc);
            acc = fmaf(p3.w, h3v, acc);
        }
        for (; e < m; ++e) {
            float4 p = lp[wbase + e];
            float h = fmaxf(fmaf(p.x, w0, fmaf(p.y, w1, fmaf(p.z, w2, bb))), 0.f);
            acc = fmaf(p.w, h, acc);
        }
    }
    agg1[t] = acc;   // NO bias/relu here: h2 = relu(agg1 @ W2 + b2)
}

// ---------------- fused register-tiled GEMM + pool --------------------------------
__global__ void k_mm2pool(const float* __restrict__ agg1, const float* __restrict__ W2,
                          const float* __restrict__ b2, const int* __restrict__ batch,
                          float* __restrict__ pooled) {
    __shared__ float wt[C_H1 * C_H2];   // 32 KiB
    __shared__ float at[64 * C_H1];     // 16 KiB
    int tid = threadIdx.x;
    {
        const float4* w4 = (const float4*)W2;
        float4* wl = (float4*)wt;
        for (int i = tid; i < (C_H1 * C_H2) / 4; i += 256) wl[i] = w4[i];
        const float4* a4 = (const float4*)(agg1 + (size_t)blockIdx.x * 64 * C_H1);
        float4* al = (float4*)at;
        for (int i = tid; i < (64 * C_H1) / 4; i += 256) al[i] = a4[i];
    }
    __syncthreads();

    int tx = tid & 31;
    int my = tid >> 5;
    int c0 = tx * 4;
    int m0 = my * 8;

    float acc[8][4];
#pragma unroll
    for (int i = 0; i < 8; ++i)
#pragma unroll
        for (int j = 0; j < 4; ++j) acc[i][j] = 0.f;

    for (int k0 = 0; k0 < C_H1; k0 += 4) {
        float4 wf[4];
#pragma unroll
        for (int kk = 0; kk < 4; ++kk)
            wf[kk] = *(const float4*)&wt[(k0 + kk) * C_H2 + c0];
#pragma unroll
        for (int i = 0; i < 8; ++i) {
            float4 af = *(const float4*)&at[(m0 + i) * C_H1 + k0];
            acc[i][0] = fmaf(af.x, wf[0].x, acc[i][0]);
            acc[i][1] = fmaf(af.x, wf[0].y, acc[i][1]);
            acc[i][2] = fmaf(af.x, wf[0].z, acc[i][2]);
            acc[i][3] = fmaf(af.x, wf[0].w, acc[i][3]);
            acc[i][0] = fmaf(af.y, wf[1].x, acc[i][0]);
            acc[i][1] = fmaf(af.y, wf[1].y, acc[i][1]);
            acc[i][2] = fmaf(af.y, wf[1].z, acc[i][2]);
            acc[i][3] = fmaf(af.y, wf[1].w, acc[i][3]);
            acc[i][0] = fmaf(af.z, wf[2].x, acc[i][0]);
            acc[i][1] = fmaf(af.z, wf[2].y, acc[i][1]);
            acc[i][2] = fmaf(af.z, wf[2].z, acc[i][2]);
            acc[i][3] = fmaf(af.z, wf[2].w, acc[i][3]);
            acc[i][0] = fmaf(af.w, wf[3].x, acc[i][0]);
            acc[i][1] = fmaf(af.w, wf[3].y, acc[i][1]);
            acc[i][2] = fmaf(af.w, wf[3].z, acc[i][2]);
            acc[i][3] = fmaf(af.w, wf[3].w, acc[i][3]);
        }
    }

    int nbase = blockIdx.x * 64 + m0;
    int gidx[8];
#pragma unroll
    for (int i = 0; i < 8; ++i)
        gidx[i] = (nbase + i < NN) ? batch[nbase + i] : -1;
    float bias[4];
#pragma unroll
    for (int j = 0; j < 4; ++j) bias[j] = b2[c0 + j];

#pragma unroll
    for (int j = 0; j < 4; ++j) {
        int run_g = -1;
        float rs = 0.f;
#pragma unroll
        for (int i = 0; i < 8; ++i) {
            if (gidx[i] < 0) break;
            float h = fmaxf(acc[i][j] + bias[j], 0.f);
            if (gidx[i] != run_g) {
                if (run_g >= 0) atomicAdd(&pooled[(run_g << 7) + c0 + j], rs);
                run_g = gidx[i]; rs = h;
            } else {
                rs += h;
            }
        }
        if (run_g >= 0) atomicAdd(&pooled[(run_g << 7) + c0 + j], rs);
    }
}

// ---------------- FC: out = (pooled/cnt) @ Wfc + bfc ----------------
__device__ __forceinline__ int lower_bound(const int* __restrict__ a, int n, int key) {
    int lo = 0, hi = n;
    while (lo < hi) { int mid = (lo + hi) >> 1; if (a[mid] < key) lo = mid + 1; else hi = mid; }
    return lo;
}

__global__ void k_fc(const float* __restrict__ pooled, const int* __restrict__ batch,
                     const float* __restrict__ Wfc, const float* __restrict__ bfc,
                     float* __restrict__ out) {
    int t = blockIdx.x * blockDim.x + threadIdx.x;
    if (t >= NG * C_OUT) return;
    int g = t >> 1, o = t & 1;
    int start = lower_bound(batch, NN, g);
    int end   = lower_bound(batch, NN, g + 1);
    float inv = 1.f / fmaxf((float)(end - start), 1.f);
    float s = bfc[o];
    for (int cc = 0; cc < C_H2; ++cc)
        s = fmaf(pooled[(g << 7) + cc] * inv, Wfc[cc * C_OUT + o], s);
    out[t] = s;
}

extern "C" void kernel_launch(void* const* d_in, const int* in_sizes, int n_in,
                              void* d_out, int out_size, void* d_ws, size_t ws_size,
                              hipStream_t stream) {
    const float* x     = (const float*)d_in[0];
    const int*   ei    = (const int*)d_in[1];   // [2, E]: row0 = src, row1 = dst
    const int*   batch = (const int*)d_in[2];
    const float* W1    = (const float*)d_in[3];
    const float* b1    = (const float*)d_in[4];
    const float* W2    = (const float*)d_in[5];
    const float* b2    = (const float*)d_in[6];
    const float* Wfc   = (const float*)d_in[7];
    const float* bfc   = (const float*)d_in[8];
    float* out = (float*)d_out;

    // workspace carve-out (~95 MB)
    char* p = (char*)d_ws;
    auto alloc = [&](size_t bytes) { char* r = p; p += (bytes + 255) & ~size_t(255); return r; };
    float*  dinv    = (float*) alloc((size_t)NN * 4);
    int*    row_ptr = (int*)   alloc((size_t)(NN + 1) * 4);
    int*    btot    = (int*)   alloc((size_t)NB * 4);
    int*    bbase   = (int*)   alloc((size_t)(NB + 1) * 4);
    int*    hist    = (int*)   alloc((size_t)NB * PCHUNKS * 4);
    int*    offs    = (int*)   alloc((size_t)NB * PCHUNKS * 4);
    int2*   ed2     = (int2*)  alloc((size_t)NE * 8);
    int2*   ed      = (int2*)  alloc((size_t)NE * 8);
    float*  aggx    = (float*) alloc((size_t)NN * 3 * 4);
    float4* pay     = (float4*)alloc((size_t)NE * 16);
    float*  agg1    = (float*) alloc((size_t)(NN + 64) * C_H1 * 4);  // padded
    float*  pooled  = (float*) alloc((size_t)NG * C_H2 * 4);

    hipMemsetAsync(pooled, 0, (size_t)NG * C_H2 * 4, stream);
    k_hist    <<<PCHUNKS, 256, 0, stream>>>(ei, hist);
    k_colscan0<<<NB, 256, 0, stream>>>(hist, offs, btot);
    k_bbase   <<<1, 256, 0, stream>>>(btot, bbase, row_ptr);
    k_scatterA<<<PCHUNKS, 256, 0, stream>>>(ei, offs, bbase, ed2);
    k_B1      <<<NB, 256, 0, stream>>>(ed2, bbase, dinv, row_ptr);
    k_scatterB<<<NB, 256, 0, stream>>>(row_ptr, ed2, dinv, ed);
    k_aggx    <<<(NN + 255) / 256, 256, 0, stream>>>(row_ptr, ed, dinv, x, aggx);
    k_pay     <<<NE / 256, 256, 0, stream>>>(ed, aggx, pay);
    k_edge1   <<<(NN * C_H1) / 256, 256, 0, stream>>>(row_ptr, pay, aggx, dinv, W1, b1, agg1);
    k_mm2pool <<<MM2_BLOCKS, 256, 0, stream>>>(agg1, W2, b2, batch, pooled);
    k_fc      <<<(NG * C_OUT + 255) / 256, 256, 0, stream>>>(pooled, batch, Wfc, bfc, out);
}

// Round 11
// 241.895 us; speedup vs baseline: 3.6923x; 1.0089x over previous
//
#include <hip/hip_runtime.h>

#define NN 100000     // nodes
#define NE 1600000    // edges
#define NG 512        // graphs
#define C_H1 64
#define C_H2 128
#define C_OUT 2

#define MM2_BLOCKS ((NN + 127) / 128)                 // 782 (128 nodes/block, 2 tiles)
#define NB ((NN + 255) >> 8)                          // 391 dst-buckets of 256 nodes
#define PCHUNKS 512                                   // partition chunks
#define PCHUNK_E (NE / PCHUNKS)                       // 3125 edges per chunk

// ---------------- radix partition phase 1: per-chunk bucket histograms -----------
__global__ void k_hist(const int* __restrict__ ei, int* __restrict__ hist) {
    __shared__ int lh[NB];
    int tid = threadIdx.x;
    int blk = blockIdx.x;
    for (int i = tid; i < NB; i += 256) lh[i] = 0;
    __syncthreads();
    int base = blk * PCHUNK_E;
    for (int e = base + tid; e < base + PCHUNK_E; e += 256)
        atomicAdd(&lh[ei[NE + e] >> 8], 1);
    __syncthreads();
    for (int i = tid; i < NB; i += 256) hist[i * PCHUNKS + blk] = lh[i];
}

// ---------------- phase 2a: per-bucket scan over chunks (bucket-relative) --------
__global__ void k_colscan0(const int* __restrict__ hist, int* __restrict__ offs,
                           int* __restrict__ btot) {
    __shared__ int sh[256];
    int b = blockIdx.x;
    int tid = threadIdx.x;
    int v0 = hist[b * PCHUNKS + 2 * tid];
    int v1 = hist[b * PCHUNKS + 2 * tid + 1];
    sh[tid] = v0 + v1;
    __syncthreads();
    for (int off = 1; off < 256; off <<= 1) {
        int v = (tid >= off) ? sh[tid - off] : 0;
        __syncthreads();
        sh[tid] += v;
        __syncthreads();
    }
    int base = (tid == 0) ? 0 : sh[tid - 1];
    offs[b * PCHUNKS + 2 * tid]     = base;
    offs[b * PCHUNKS + 2 * tid + 1] = base + v0;
    if (tid == 255) btot[b] = sh[255];
}

// ---------------- phase 2b: exclusive scan of 391 bucket totals ------------------
__global__ void k_bbase(const int* __restrict__ btot, int* __restrict__ bbase,
                        int* __restrict__ row_ptr) {
    __shared__ int sh[256];
    int tid = threadIdx.x;
    int v0 = (2 * tid     < NB) ? btot[2 * tid]     : 0;
    int v1 = (2 * tid + 1 < NB) ? btot[2 * tid + 1] : 0;
    sh[tid] = v0 + v1;
    __syncthreads();
    for (int off = 1; off < 256; off <<= 1) {
        int v = (tid >= off) ? sh[tid - off] : 0;
        __syncthreads();
        sh[tid] += v;
        __syncthreads();
    }
    int base = (tid == 0) ? 0 : sh[tid - 1];
    if (2 * tid     < NB) bbase[2 * tid]     = base;
    if (2 * tid + 1 < NB) bbase[2 * tid + 1] = base + v0;
    if (tid == 255) { bbase[NB] = sh[255]; row_ptr[NN] = sh[255]; }   // == NE
}

// ---------------- phase 3: scatter via LDS cursors (no global atomics) -----------
__global__ void k_scatterA(const int* __restrict__ ei, const int* __restrict__ offs,
                           const int* __restrict__ bbase, int2* __restrict__ ed2) {
    __shared__ int lcur[NB];
    int tid = threadIdx.x;
    int blk = blockIdx.x;
    for (int i = tid; i < NB; i += 256) lcur[i] = bbase[i] + offs[i * PCHUNKS + blk];
    __syncthreads();
    int base = blk * PCHUNK_E;
    for (int e = base + tid; e < base + PCHUNK_E; e += 256) {
        int s = ei[e], d = ei[NE + e];
        int pos = atomicAdd(&lcur[d >> 8], 1);     // LDS atomic, low contention
        int2 v; v.x = s; v.y = d;
        ed2[pos] = v;
    }
}

// ---------------- B1: bucket-local degree -> dinv + row_ptr (no global atomics) --
__global__ void k_B1(const int2* __restrict__ ed2, const int* __restrict__ bbase,
                     float* __restrict__ dinv, int* __restrict__ row_ptr) {
    __shared__ int ldeg[256];
    __shared__ int sh[256];
    int b = blockIdx.x;
    int tid = threadIdx.x;
    int lo = b << 8;
    ldeg[tid] = 0;
    __syncthreads();
    int beg = bbase[b], end = bbase[b + 1];
    for (int j = beg + tid; j < end; j += 256)
        atomicAdd(&ldeg[ed2[j].y - lo], 1);
    __syncthreads();
    int d = ldeg[tid];
    int node = lo + tid;
    if (node < NN) dinv[node] = rsqrtf((float)d + 1.0f);
    sh[tid] = d;
    __syncthreads();
    for (int off = 1; off < 256; off <<= 1) {
        int v = (tid >= off) ? sh[tid - off] : 0;
        __syncthreads();
        sh[tid] += v;
        __syncthreads();
    }
    int excl = beg + ((tid == 0) ? 0 : sh[tid - 1]);
    if (node < NN) row_ptr[node] = excl;
}

// ---------------- repack x to float4 rows (16B gathers downstream) ---------------
__global__ void k_x4(const float* __restrict__ x, float4* __restrict__ x4) {
    int n = blockIdx.x * blockDim.x + threadIdx.x;
    if (n >= NN) return;
    float4 v; v.x = x[n * 3]; v.y = x[n * 3 + 1]; v.z = x[n * 3 + 2]; v.w = 0.f;
    x4[n] = v;
}

// ---------------- scatter pass B + fused layer-1 aggregation ---------------------
// Resolves final CSR (ed with norm) AND accumulates aggx4 = Ahat @ x via
// bucket-local LDS float atomics (all incoming edges of a node live in its bucket).
__global__ void k_scatterB(const int* __restrict__ row_ptr, const int2* __restrict__ ed2,
                           const float* __restrict__ dinv, const float4* __restrict__ x4,
                           int2* __restrict__ ed, float4* __restrict__ aggx4) {
    __shared__ int   lcur[256];
    __shared__ float ldin[256];
    __shared__ float lax[256 * 3];
    int b = blockIdx.x;
    int lo = b << 8;
    int tid = threadIdx.x;
    int node = lo + tid;
    if (node <= NN) lcur[tid] = row_ptr[node < NN ? node : NN];
    else            lcur[tid] = 0;
    ldin[tid] = (node < NN) ? dinv[node] : 0.f;
    lax[tid] = 0.f; lax[256 + tid] = 0.f; lax[512 + tid] = 0.f;
    __syncthreads();
    int seg_beg = row_ptr[lo];
    int hi = lo + 256; if (hi > NN) hi = NN;
    int seg_end = row_ptr[hi];
    for (int j = seg_beg + tid; j < seg_end; j += 256) {
        int2 sd = ed2[j];
        int local = sd.y - lo;
        int pos = atomicAdd(&lcur[local], 1);
        float nrm = dinv[sd.x] * ldin[local];
        int2 v; v.x = sd.x; v.y = __float_as_int(nrm);
        ed[pos] = v;
        float4 xs = x4[sd.x];                          // 16B gather, L2-hot (1.6MB)
        atomicAdd(&lax[local],       nrm * xs.x);      // ds_add_f32
        atomicAdd(&lax[256 + local], nrm * xs.y);
        atomicAdd(&lax[512 + local], nrm * xs.z);
    }
    __syncthreads();
    if (node < NN) {
        float di = ldin[tid];
        float s2 = di * di;
        float4 xs = x4[node];
        float4 a;
        a.x = lax[tid]       + s2 * xs.x;
        a.y = lax[256 + tid] + s2 * xs.y;
        a.z = lax[512 + tid] + s2 * xs.z;
        a.w = 0.f;
        aggx4[node] = a;
    }
}

// ---------------- layer 2 aggregate via on-the-fly h1 recompute ------------------
// agg1[n][c] = dinv_n^2*h1(n)[c] + sum_e norm_e * h1(src_e)[c],
// h1(m)[c] = relu(aggx4[m]·W1[:,c] + b1[c]). Edge staging: per-lane coalesced
// ed read + 16B aggx4[src] gather (L2-hot) -> LDS; consume via broadcast.
__global__ void k_edge1(const int* __restrict__ row_ptr, const int2* __restrict__ ed,
                        const float4* __restrict__ aggx4, const float* __restrict__ dinv,
                        const float* __restrict__ W1, const float* __restrict__ b1,
                        float* __restrict__ agg1) {
    __shared__ float4 lp[256];                        // 64 per wave
    int t = blockIdx.x * 256 + threadIdx.x;           // grid exact: NN*64/256
    int n = t >> 6, c = t & 63;
    int lane = threadIdx.x & 63;
    int wbase = threadIdx.x & 192;                    // wave's LDS base (0,64,128,192)

    float w0 = W1[c], w1 = W1[64 + c], w2 = W1[128 + c], bb = b1[c];
    float4 an = aggx4[n];                             // wave-uniform
    float di = dinv[n];
    float hself = fmaxf(fmaf(an.x, w0, fmaf(an.y, w1, fmaf(an.z, w2, bb))), 0.f);
    float acc = di * di * hself;

    int beg = row_ptr[n], end = row_ptr[n + 1];
    for (int base = beg; base < end; base += 64) {
        int m = end - base; if (m > 64) m = 64;
        if (lane < m) {
            int2 v = ed[base + lane];                 // coalesced 8B
            float4 ax = aggx4[v.x];                   // random 16B, L2-hot
            float4 p; p.x = ax.x; p.y = ax.y; p.z = ax.z; p.w = __int_as_float(v.y);
            lp[wbase + lane] = p;
        }
        int e = 0;
        for (; e + 3 < m; e += 4) {
            float4 p0 = lp[wbase + e];
            float4 p1 = lp[wbase + e + 1];
            float4 p2 = lp[wbase + e + 2];
            float4 p3 = lp[wbase + e + 3];
            float h0  = fmaxf(fmaf(p0.x, w0, fmaf(p0.y, w1, fmaf(p0.z, w2, bb))), 0.f);
            float h1v = fmaxf(fmaf(p1.x, w0, fmaf(p1.y, w1, fmaf(p1.z, w2, bb))), 0.f);
            float h2v = fmaxf(fmaf(p2.x, w0, fmaf(p2.y, w1, fmaf(p2.z, w2, bb))), 0.f);
            float h3v = fmaxf(fmaf(p3.x, w0, fmaf(p3.y, w1, fmaf(p3.z, w2, bb))), 0.f);
            acc = fmaf(p0.w, h0, acc);
            acc = fmaf(p1.w, h1v, acc);
            acc = fmaf(p2.w, h2v, acc);
            acc = fmaf(p3.w, h3v, acc);
        }
        for (; e < m; ++e) {
            float4 p = lp[wbase + e];
            float h = fmaxf(fmaf(p.x, w0, fmaf(p.y, w1, fmaf(p.z, w2, bb))), 0.f);
            acc = fmaf(p.w, h, acc);
        }
    }
    agg1[t] = acc;   // NO bias/relu here: h2 = relu(agg1 @ W2 + b2)
}

// ---------------- fused register-tiled GEMM + pool --------------------------------
// 128 nodes/block as 2 sequential 64-node tiles; W2 staged in LDS ONCE per block.
__global__ void k_mm2pool(const float* __restrict__ agg1, const float* __restrict__ W2,
                          const float* __restrict__ b2, const int* __restrict__ batch,
                          float* __restrict__ pooled) {
    __shared__ float wt[C_H1 * C_H2];   // 32 KiB
    __shared__ float at[64 * C_H1];     // 16 KiB
    int tid = threadIdx.x;
    {
        const float4* w4 = (const float4*)W2;
        float4* wl = (float4*)wt;
        for (int i = tid; i < (C_H1 * C_H2) / 4; i += 256) wl[i] = w4[i];
    }
    int tx = tid & 31;
    int my = tid >> 5;
    int c0 = tx * 4;
    int m0 = my * 8;
    float bias[4];
#pragma unroll
    for (int j = 0; j < 4; ++j) bias[j] = b2[c0 + j];

    for (int tile = 0; tile < 2; ++tile) {
        // stage A-tile (prev tile fully consumed: barrier below each compute)
        {
            const float4* a4 = (const float4*)(agg1 + ((size_t)blockIdx.x * 128 + tile * 64) * C_H1);
            float4* al = (float4*)at;
            for (int i = tid; i < (64 * C_H1) / 4; i += 256) al[i] = a4[i];
        }
        __syncthreads();

        float acc[8][4];
#pragma unroll
        for (int i = 0; i < 8; ++i)
#pragma unroll
            for (int j = 0; j < 4; ++j) acc[i][j] = 0.f;

        for (int k0 = 0; k0 < C_H1; k0 += 4) {
            float4 wf[4];
#pragma unroll
            for (int kk = 0; kk < 4; ++kk)
                wf[kk] = *(const float4*)&wt[(k0 + kk) * C_H2 + c0];
#pragma unroll
            for (int i = 0; i < 8; ++i) {
                float4 af = *(const float4*)&at[(m0 + i) * C_H1 + k0];
                acc[i][0] = fmaf(af.x, wf[0].x, acc[i][0]);
                acc[i][1] = fmaf(af.x, wf[0].y, acc[i][1]);
                acc[i][2] = fmaf(af.x, wf[0].z, acc[i][2]);
                acc[i][3] = fmaf(af.x, wf[0].w, acc[i][3]);
                acc[i][0] = fmaf(af.y, wf[1].x, acc[i][0]);
                acc[i][1] = fmaf(af.y, wf[1].y, acc[i][1]);
                acc[i][2] = fmaf(af.y, wf[1].z, acc[i][2]);
                acc[i][3] = fmaf(af.y, wf[1].w, acc[i][3]);
                acc[i][0] = fmaf(af.z, wf[2].x, acc[i][0]);
                acc[i][1] = fmaf(af.z, wf[2].y, acc[i][1]);
                acc[i][2] = fmaf(af.z, wf[2].z, acc[i][2]);
                acc[i][3] = fmaf(af.z, wf[2].w, acc[i][3]);
                acc[i][0] = fmaf(af.w, wf[3].x, acc[i][0]);
                acc[i][1] = fmaf(af.w, wf[3].y, acc[i][1]);
                acc[i][2] = fmaf(af.w, wf[3].z, acc[i][2]);
                acc[i][3] = fmaf(af.w, wf[3].w, acc[i][3]);
            }
        }

        int nbase = blockIdx.x * 128 + tile * 64 + m0;
        int gidx[8];
#pragma unroll
        for (int i = 0; i < 8; ++i)
            gidx[i] = (nbase + i < NN) ? batch[nbase + i] : -1;

#pragma unroll
        for (int j = 0; j < 4; ++j) {
            int run_g = -1;
            float rs = 0.f;
#pragma unroll
            for (int i = 0; i < 8; ++i) {
                if (gidx[i] < 0) break;
                float h = fmaxf(acc[i][j] + bias[j], 0.f);
                if (gidx[i] != run_g) {
                    if (run_g >= 0) atomicAdd(&pooled[(run_g << 7) + c0 + j], rs);
                    run_g = gidx[i]; rs = h;
                } else {
                    rs += h;
                }
            }
            if (run_g >= 0) atomicAdd(&pooled[(run_g << 7) + c0 + j], rs);
        }
        __syncthreads();   // all waves done reading at[] before next tile staging
    }
}

// ---------------- FC: out = (pooled/cnt) @ Wfc + bfc ----------------
__device__ __forceinline__ int lower_bound(const int* __restrict__ a, int n, int key) {
    int lo = 0, hi = n;
    while (lo < hi) { int mid = (lo + hi) >> 1; if (a[mid] < key) lo = mid + 1; else hi = mid; }
    return lo;
}

__global__ void k_fc(const float* __restrict__ pooled, const int* __restrict__ batch,
                     const float* __restrict__ Wfc, const float* __restrict__ bfc,
                     float* __restrict__ out) {
    int t = blockIdx.x * blockDim.x + threadIdx.x;
    if (t >= NG * C_OUT) return;
    int g = t >> 1, o = t & 1;
    int start = lower_bound(batch, NN, g);
    int end   = lower_bound(batch, NN, g + 1);
    float inv = 1.f / fmaxf((float)(end - start), 1.f);
    float s = bfc[o];
    for (int cc = 0; cc < C_H2; ++cc)
        s = fmaf(pooled[(g << 7) + cc] * inv, Wfc[cc * C_OUT + o], s);
    out[t] = s;
}

extern "C" void kernel_launch(void* const* d_in, const int* in_sizes, int n_in,
                              void* d_out, int out_size, void* d_ws, size_t ws_size,
                              hipStream_t stream) {
    const float* x     = (const float*)d_in[0];
    const int*   ei    = (const int*)d_in[1];   // [2, E]: row0 = src, row1 = dst
    const int*   batch = (const int*)d_in[2];
    const float* W1    = (const float*)d_in[3];
    const float* b1    = (const float*)d_in[4];
    const float* W2    = (const float*)d_in[5];
    const float* b2    = (const float*)d_in[6];
    const float* Wfc   = (const float*)d_in[7];
    const float* bfc   = (const float*)d_in[8];
    float* out = (float*)d_out;

    // workspace carve-out (~58 MB)
    char* p = (char*)d_ws;
    auto alloc = [&](size_t bytes) { char* r = p; p += (bytes + 255) & ~size_t(255); return r; };
    float*  dinv    = (float*) alloc((size_t)NN * 4);
    int*    row_ptr = (int*)   alloc((size_t)(NN + 1) * 4);
    int*    btot    = (int*)   alloc((size_t)NB * 4);
    int*    bbase   = (int*)   alloc((size_t)(NB + 1) * 4);
    int*    hist    = (int*)   alloc((size_t)NB * PCHUNKS * 4);
    int*    offs    = (int*)   alloc((size_t)NB * PCHUNKS * 4);
    int2*   ed2     = (int2*)  alloc((size_t)NE * 8);
    int2*   ed      = (int2*)  alloc((size_t)NE * 8);
    float4* x4      = (float4*)alloc((size_t)NN * 16);
    float4* aggx4   = (float4*)alloc((size_t)NN * 16);
    float*  agg1    = (float*) alloc((size_t)(NN + 128) * C_H1 * 4);  // padded
    float*  pooled  = (float*) alloc((size_t)NG * C_H2 * 4);

    hipMemsetAsync(pooled, 0, (size_t)NG * C_H2 * 4, stream);
    k_hist    <<<PCHUNKS, 256, 0, stream>>>(ei, hist);
    k_colscan0<<<NB, 256, 0, stream>>>(hist, offs, btot);
    k_bbase   <<<1, 256, 0, stream>>>(btot, bbase, row_ptr);
    k_scatterA<<<PCHUNKS, 256, 0, stream>>>(ei, offs, bbase, ed2);
    k_B1      <<<NB, 256, 0, stream>>>(ed2, bbase, dinv, row_ptr);
    k_x4      <<<(NN + 255) / 256, 256, 0, stream>>>(x, x4);
    k_scatterB<<<NB, 256, 0, stream>>>(row_ptr, ed2, dinv, x4, ed, aggx4);
    k_edge1   <<<(NN * C_H1) / 256, 256, 0, stream>>>(row_ptr, ed, aggx4, dinv, W1, b1, agg1);
    k_mm2pool <<<MM2_BLOCKS, 256, 0, stream>>>(agg1, W2, b2, batch, pooled);
    k_fc      <<<(NG * C_OUT + 255) / 256, 256, 0, stream>>>(pooled, batch, Wfc, bfc, out);
}

// Round 12
// 231.122 us; speedup vs baseline: 3.8644x; 1.0466x over previous
//
#include <hip/hip_runtime.h>

#define NN 100000     // nodes
#define NE 1600000    // edges
#define NG 512        // graphs
#define C_H1 64
#define C_H2 128
#define C_OUT 2

#define MM2_BLOCKS ((NN + 127) / 128)                 // 782 (128 nodes/block)
#define NB ((NN + 255) >> 8)                          // 391 dst-buckets of 256 nodes
#define PCHUNKS 512                                   // partition chunks
#define PCHUNK_E (NE / PCHUNKS)                       // 3125 edges per chunk
#define AT_S 68                                       // padded A-tile row stride (16B-aligned)

// ---------------- radix partition phase 1: per-chunk bucket histograms -----------
__global__ void k_hist(const int* __restrict__ ei, int* __restrict__ hist) {
    __shared__ int lh[NB];
    int tid = threadIdx.x;
    int blk = blockIdx.x;
    for (int i = tid; i < NB; i += 256) lh[i] = 0;
    __syncthreads();
    int base = blk * PCHUNK_E;
    for (int e = base + tid; e < base + PCHUNK_E; e += 256)
        atomicAdd(&lh[ei[NE + e] >> 8], 1);
    __syncthreads();
    for (int i = tid; i < NB; i += 256) hist[i * PCHUNKS + blk] = lh[i];
}

// ---------------- phase 2a: per-bucket scan over chunks (bucket-relative) --------
__global__ void k_colscan0(const int* __restrict__ hist, int* __restrict__ offs,
                           int* __restrict__ btot) {
    __shared__ int sh[256];
    int b = blockIdx.x;
    int tid = threadIdx.x;
    int v0 = hist[b * PCHUNKS + 2 * tid];
    int v1 = hist[b * PCHUNKS + 2 * tid + 1];
    sh[tid] = v0 + v1;
    __syncthreads();
    for (int off = 1; off < 256; off <<= 1) {
        int v = (tid >= off) ? sh[tid - off] : 0;
        __syncthreads();
        sh[tid] += v;
        __syncthreads();
    }
    int base = (tid == 0) ? 0 : sh[tid - 1];
    offs[b * PCHUNKS + 2 * tid]     = base;
    offs[b * PCHUNKS + 2 * tid + 1] = base + v0;
    if (tid == 255) btot[b] = sh[255];
}

// ---------------- phase 2b: exclusive scan of 391 bucket totals ------------------
__global__ void k_bbase(const int* __restrict__ btot, int* __restrict__ bbase,
                        int* __restrict__ row_ptr) {
    __shared__ int sh[256];
    int tid = threadIdx.x;
    int v0 = (2 * tid     < NB) ? btot[2 * tid]     : 0;
    int v1 = (2 * tid + 1 < NB) ? btot[2 * tid + 1] : 0;
    sh[tid] = v0 + v1;
    __syncthreads();
    for (int off = 1; off < 256; off <<= 1) {
        int v = (tid >= off) ? sh[tid - off] : 0;
        __syncthreads();
        sh[tid] += v;
        __syncthreads();
    }
    int base = (tid == 0) ? 0 : sh[tid - 1];
    if (2 * tid     < NB) bbase[2 * tid]     = base;
    if (2 * tid + 1 < NB) bbase[2 * tid + 1] = base + v0;
    if (tid == 255) { bbase[NB] = sh[255]; row_ptr[NN] = sh[255]; }   // == NE
}

// ---------------- phase 3: scatter via LDS cursors (no global atomics) -----------
__global__ void k_scatterA(const int* __restrict__ ei, const int* __restrict__ offs,
                           const int* __restrict__ bbase, int2* __restrict__ ed2) {
    __shared__ int lcur[NB];
    int tid = threadIdx.x;
    int blk = blockIdx.x;
    for (int i = tid; i < NB; i += 256) lcur[i] = bbase[i] + offs[i * PCHUNKS + blk];
    __syncthreads();
    int base = blk * PCHUNK_E;
    for (int e = base + tid; e < base + PCHUNK_E; e += 256) {
        int s = ei[e], d = ei[NE + e];
        int pos = atomicAdd(&lcur[d >> 8], 1);     // LDS atomic, low contention
        int2 v; v.x = s; v.y = d;
        ed2[pos] = v;
    }
}

// ---------------- B1: bucket-local degree -> dinv + row_ptr (no global atomics) --
__global__ void k_B1(const int2* __restrict__ ed2, const int* __restrict__ bbase,
                     float* __restrict__ dinv, int* __restrict__ row_ptr) {
    __shared__ int ldeg[256];
    __shared__ int sh[256];
    int b = blockIdx.x;
    int tid = threadIdx.x;
    int lo = b << 8;
    ldeg[tid] = 0;
    __syncthreads();
    int beg = bbase[b], end = bbase[b + 1];
    for (int j = beg + tid; j < end; j += 256)
        atomicAdd(&ldeg[ed2[j].y - lo], 1);
    __syncthreads();
    int d = ldeg[tid];
    int node = lo + tid;
    if (node < NN) dinv[node] = rsqrtf((float)d + 1.0f);
    sh[tid] = d;
    __syncthreads();
    for (int off = 1; off < 256; off <<= 1) {
        int v = (tid >= off) ? sh[tid - off] : 0;
        __syncthreads();
        sh[tid] += v;
        __syncthreads();
    }
    int excl = beg + ((tid == 0) ? 0 : sh[tid - 1]);
    if (node < NN) row_ptr[node] = excl;
}

// ---------------- repack x to float4 rows (16B gathers downstream) ---------------
__global__ void k_x4(const float* __restrict__ x, float4* __restrict__ x4) {
    int n = blockIdx.x * blockDim.x + threadIdx.x;
    if (n >= NN) return;
    float4 v; v.x = x[n * 3]; v.y = x[n * 3 + 1]; v.z = x[n * 3 + 2]; v.w = 0.f;
    x4[n] = v;
}

// ---------------- scatter pass B + fused layer-1 aggregation ---------------------
__global__ void k_scatterB(const int* __restrict__ row_ptr, const int2* __restrict__ ed2,
                           const float* __restrict__ dinv, const float4* __restrict__ x4,
                           int2* __restrict__ ed, float4* __restrict__ aggx4) {
    __shared__ int   lcur[256];
    __shared__ float ldin[256];
    __shared__ float lax[256 * 3];
    int b = blockIdx.x;
    int lo = b << 8;
    int tid = threadIdx.x;
    int node = lo + tid;
    if (node <= NN) lcur[tid] = row_ptr[node < NN ? node : NN];
    else            lcur[tid] = 0;
    ldin[tid] = (node < NN) ? dinv[node] : 0.f;
    lax[tid] = 0.f; lax[256 + tid] = 0.f; lax[512 + tid] = 0.f;
    __syncthreads();
    int seg_beg = row_ptr[lo];
    int hi = lo + 256; if (hi > NN) hi = NN;
    int seg_end = row_ptr[hi];
    for (int j = seg_beg + tid; j < seg_end; j += 256) {
        int2 sd = ed2[j];
        int local = sd.y - lo;
        int pos = atomicAdd(&lcur[local], 1);
        float nrm = dinv[sd.x] * ldin[local];
        int2 v; v.x = sd.x; v.y = __float_as_int(nrm);
        ed[pos] = v;
        float4 xs = x4[sd.x];                          // 16B gather, L2-hot (1.6MB)
        atomicAdd(&lax[local],       nrm * xs.x);      // ds_add_f32
        atomicAdd(&lax[256 + local], nrm * xs.y);
        atomicAdd(&lax[512 + local], nrm * xs.z);
    }
    __syncthreads();
    if (node < NN) {
        float di = ldin[tid];
        float s2 = di * di;
        float4 xs = x4[node];
        float4 a;
        a.x = lax[tid]       + s2 * xs.x;
        a.y = lax[256 + tid] + s2 * xs.y;
        a.z = lax[512 + tid] + s2 * xs.z;
        a.w = 0.f;
        aggx4[node] = a;
    }
}

// ---------------- layer 2 aggregate via on-the-fly h1 recompute ------------------
__global__ void k_edge1(const int* __restrict__ row_ptr, const int2* __restrict__ ed,
                        const float4* __restrict__ aggx4, const float* __restrict__ dinv,
                        const float* __restrict__ W1, const float* __restrict__ b1,
                        float* __restrict__ agg1) {
    __shared__ float4 lp[256];                        // 64 per wave
    int t = blockIdx.x * 256 + threadIdx.x;           // grid exact: NN*64/256
    int n = t >> 6, c = t & 63;
    int lane = threadIdx.x & 63;
    int wbase = threadIdx.x & 192;                    // wave's LDS base (0,64,128,192)

    float w0 = W1[c], w1 = W1[64 + c], w2 = W1[128 + c], bb = b1[c];
    float4 an = aggx4[n];                             // wave-uniform
    float di = dinv[n];
    float hself = fmaxf(fmaf(an.x, w0, fmaf(an.y, w1, fmaf(an.z, w2, bb))), 0.f);
    float acc = di * di * hself;

    int beg = row_ptr[n], end = row_ptr[n + 1];
    for (int base = beg; base < end; base += 64) {
        int m = end - base; if (m > 64) m = 64;
        if (lane < m) {
            int2 v = ed[base + lane];                 // coalesced 8B
            float4 ax = aggx4[v.x];                   // random 16B, L2-hot
            float4 p; p.x = ax.x; p.y = ax.y; p.z = ax.z; p.w = __int_as_float(v.y);
            lp[wbase + lane] = p;
        }
        int e = 0;
        for (; e + 3 < m; e += 4) {
            float4 p0 = lp[wbase + e];
            float4 p1 = lp[wbase + e + 1];
            float4 p2 = lp[wbase + e + 2];
            float4 p3 = lp[wbase + e + 3];
            float h0  = fmaxf(fmaf(p0.x, w0, fmaf(p0.y, w1, fmaf(p0.z, w2, bb))), 0.f);
            float h1v = fmaxf(fmaf(p1.x, w0, fmaf(p1.y, w1, fmaf(p1.z, w2, bb))), 0.f);
            float h2v = fmaxf(fmaf(p2.x, w0, fmaf(p2.y, w1, fmaf(p2.z, w2, bb))), 0.f);
            float h3v = fmaxf(fmaf(p3.x, w0, fmaf(p3.y, w1, fmaf(p3.z, w2, bb))), 0.f);
            acc = fmaf(p0.w, h0, acc);
            acc = fmaf(p1.w, h1v, acc);
            acc = fmaf(p2.w, h2v, acc);
            acc = fmaf(p3.w, h3v, acc);
        }
        for (; e < m; ++e) {
            float4 p = lp[wbase + e];
            float h = fmaxf(fmaf(p.x, w0, fmaf(p.y, w1, fmaf(p.z, w2, bb))), 0.f);
            acc = fmaf(p.w, h, acc);
        }
    }
    agg1[t] = acc;   // NO bias/relu here: h2 = relu(agg1 @ W2 + b2)
}

// ---------------- fused register-tiled GEMM + pool (v3) ---------------------------
// Block = 128 nodes x 128 ch, 256 threads, 8x8 micro-tile (my=node grp, tx=ch grp).
// A-tile 128x64 in LDS (row stride 68) + W2 32KB in LDS; two-level pooling:
// per-thread run-length -> LDS graph slots -> ~512 global atomics/block.
__global__ void k_mm2pool(const float* __restrict__ agg1, const float* __restrict__ W2,
                          const float* __restrict__ b2, const int* __restrict__ batch,
                          float* __restrict__ pooled) {
    __shared__ float wt[C_H1 * C_H2];      // 32 KiB
    __shared__ float at[128 * AT_S];       // 34 KiB
    __shared__ float lpool[4 * C_H2];      // 2 KiB
    int tid = threadIdx.x;
    {
        const float4* w4 = (const float4*)W2;
        float4* wl = (float4*)wt;
        for (int i = tid; i < (C_H1 * C_H2) / 4; i += 256) wl[i] = w4[i];
        const float4* a4 = (const float4*)(agg1 + (size_t)blockIdx.x * 128 * C_H1);
        for (int i = tid; i < 128 * 16; i += 256) {
            int row = i >> 4, k4 = i & 15;
            *(float4*)&at[row * AT_S + k4 * 4] = a4[i];   // coalesced global read
        }
        for (int i = tid; i < 4 * C_H2; i += 256) lpool[i] = 0.f;
    }
    __syncthreads();

    int tx = tid & 15;            // channel group: 8 ch
    int my = tid >> 4;            // node group: 8 consecutive nodes
    int c0 = tx * 8;
    int m0 = my * 8;

    float acc[8][8];
#pragma unroll
    for (int i = 0; i < 8; ++i)
#pragma unroll
        for (int j = 0; j < 8; ++j) acc[i][j] = 0.f;

    for (int k0 = 0; k0 < C_H1; k0 += 4) {
        float4 wf[4][2];
#pragma unroll
        for (int kk = 0; kk < 4; ++kk) {
            wf[kk][0] = *(const float4*)&wt[(k0 + kk) * C_H2 + c0];
            wf[kk][1] = *(const float4*)&wt[(k0 + kk) * C_H2 + c0 + 4];
        }
#pragma unroll
        for (int i = 0; i < 8; ++i) {
            float4 af = *(const float4*)&at[(m0 + i) * AT_S + k0];
#pragma unroll
            for (int kk = 0; kk < 4; ++kk) {
                float a = (kk == 0) ? af.x : (kk == 1) ? af.y : (kk == 2) ? af.z : af.w;
                acc[i][0] = fmaf(a, wf[kk][0].x, acc[i][0]);
                acc[i][1] = fmaf(a, wf[kk][0].y, acc[i][1]);
                acc[i][2] = fmaf(a, wf[kk][0].z, acc[i][2]);
                acc[i][3] = fmaf(a, wf[kk][0].w, acc[i][3]);
                acc[i][4] = fmaf(a, wf[kk][1].x, acc[i][4]);
                acc[i][5] = fmaf(a, wf[kk][1].y, acc[i][5]);
                acc[i][6] = fmaf(a, wf[kk][1].z, acc[i][6]);
                acc[i][7] = fmaf(a, wf[kk][1].w, acc[i][7]);
            }
        }
    }

    // epilogue: bias+relu, run-length over 8 consecutive nodes, LDS graph slots
    int nbase = blockIdx.x * 128 + m0;
    int gbase = batch[blockIdx.x * 128];               // block-uniform
    int gidx[8];
#pragma unroll
    for (int i = 0; i < 8; ++i)
        gidx[i] = (nbase + i < NN) ? batch[nbase + i] : -1;
    float bias[8];
#pragma unroll
    for (int j = 0; j < 8; ++j) bias[j] = b2[c0 + j];

#pragma unroll
    for (int j = 0; j < 8; ++j) {
        int run_g = -1;
        float rs = 0.f;
#pragma unroll
        for (int i = 0; i < 8; ++i) {
            if (gidx[i] < 0) break;
            float h = fmaxf(acc[i][j] + bias[j], 0.f);
            if (gidx[i] != run_g) {
                if (run_g >= 0) {
                    int slot = run_g - gbase;
                    if (slot < 4) atomicAdd(&lpool[slot * C_H2 + c0 + j], rs);
                    else          atomicAdd(&pooled[(run_g << 7) + c0 + j], rs);
                }
                run_g = gidx[i]; rs = h;
            } else {
                rs += h;
            }
        }
        if (run_g >= 0) {
            int slot = run_g - gbase;
            if (slot < 4) atomicAdd(&lpool[slot * C_H2 + c0 + j], rs);
            else          atomicAdd(&pooled[(run_g << 7) + c0 + j], rs);
        }
    }
    __syncthreads();
    for (int i = tid; i < 4 * C_H2; i += 256) {
        int slot = i >> 7, c = i & 127;
        int g = gbase + slot;
        float v = lpool[i];
        if (g < NG && v != 0.f) atomicAdd(&pooled[(g << 7) + c], v);
    }
}

// ---------------- FC: out = (pooled/cnt) @ Wfc + bfc ----------------
__device__ __forceinline__ int lower_bound(const int* __restrict__ a, int n, int key) {
    int lo = 0, hi = n;
    while (lo < hi) { int mid = (lo + hi) >> 1; if (a[mid] < key) lo = mid + 1; else hi = mid; }
    return lo;
}

__global__ void k_fc(const float* __restrict__ pooled, const int* __restrict__ batch,
                     const float* __restrict__ Wfc, const float* __restrict__ bfc,
                     float* __restrict__ out) {
    int t = blockIdx.x * blockDim.x + threadIdx.x;
    if (t >= NG * C_OUT) return;
    int g = t >> 1, o = t & 1;
    int start = lower_bound(batch, NN, g);
    int end   = lower_bound(batch, NN, g + 1);
    float inv = 1.f / fmaxf((float)(end - start), 1.f);
    float s = bfc[o];
    for (int cc = 0; cc < C_H2; ++cc)
        s = fmaf(pooled[(g << 7) + cc] * inv, Wfc[cc * C_OUT + o], s);
    out[t] = s;
}

extern "C" void kernel_launch(void* const* d_in, const int* in_sizes, int n_in,
                              void* d_out, int out_size, void* d_ws, size_t ws_size,
                              hipStream_t stream) {
    const float* x     = (const float*)d_in[0];
    const int*   ei    = (const int*)d_in[1];   // [2, E]: row0 = src, row1 = dst
    const int*   batch = (const int*)d_in[2];
    const float* W1    = (const float*)d_in[3];
    const float* b1    = (const float*)d_in[4];
    const float* W2    = (const float*)d_in[5];
    const float* b2    = (const float*)d_in[6];
    const float* Wfc   = (const float*)d_in[7];
    const float* bfc   = (const float*)d_in[8];
    float* out = (float*)d_out;

    // workspace carve-out (~58 MB)
    char* p = (char*)d_ws;
    auto alloc = [&](size_t bytes) { char* r = p; p += (bytes + 255) & ~size_t(255); return r; };
    float*  dinv    = (float*) alloc((size_t)NN * 4);
    int*    row_ptr = (int*)   alloc((size_t)(NN + 1) * 4);
    int*    btot    = (int*)   alloc((size_t)NB * 4);
    int*    bbase   = (int*)   alloc((size_t)(NB + 1) * 4);
    int*    hist    = (int*)   alloc((size_t)NB * PCHUNKS * 4);
    int*    offs    = (int*)   alloc((size_t)NB * PCHUNKS * 4);
    int2*   ed2     = (int2*)  alloc((size_t)NE * 8);
    int2*   ed      = (int2*)  alloc((size_t)NE * 8);
    float4* x4      = (float4*)alloc((size_t)NN * 16);
    float4* aggx4   = (float4*)alloc((size_t)NN * 16);
    float*  agg1    = (float*) alloc((size_t)(NN + 128) * C_H1 * 4);  // padded
    float*  pooled  = (float*) alloc((size_t)NG * C_H2 * 4);

    hipMemsetAsync(pooled, 0, (size_t)NG * C_H2 * 4, stream);
    k_hist    <<<PCHUNKS, 256, 0, stream>>>(ei, hist);
    k_colscan0<<<NB, 256, 0, stream>>>(hist, offs, btot);
    k_bbase   <<<1, 256, 0, stream>>>(btot, bbase, row_ptr);
    k_scatterA<<<PCHUNKS, 256, 0, stream>>>(ei, offs, bbase, ed2);
    k_B1      <<<NB, 256, 0, stream>>>(ed2, bbase, dinv, row_ptr);
    k_x4      <<<(NN + 255) / 256, 256, 0, stream>>>(x, x4);
    k_scatterB<<<NB, 256, 0, stream>>>(row_ptr, ed2, dinv, x4, ed, aggx4);
    k_edge1   <<<(NN * C_H1) / 256, 256, 0, stream>>>(row_ptr, ed, aggx4, dinv, W1, b1, agg1);
    k_mm2pool <<<MM2_BLOCKS, 256, 0, stream>>>(agg1, W2, b2, batch, pooled);
    k_fc      <<<(NG * C_OUT + 255) / 256, 256, 0, stream>>>(pooled, batch, Wfc, bfc, out);
}